// Round 5
// baseline (1244.145 us; speedup 1.0000x reference)
//
#include <hip/hip_runtime.h>
#include <stdint.h>

#define DIM 1536
#define NHEADS 12
#define HD 128
#define FFN 8960
#define SQ 3456
#define T5 512
#define LCTX 769
#define IMG 257
#define IMGP 384
#define EPSL 1e-6f

typedef __bf16 bf16;
typedef __bf16 bf16x8 __attribute__((ext_vector_type(8)));
typedef float f32x4 __attribute__((ext_vector_type(4)));

__device__ inline bf16x8 zero_bf16x8() {
  bf16x8 v;
  for (int i = 0; i < 8; i++) v[i] = (bf16)0.0f;
  return v;
}

// async 16B global -> LDS. lds base must be wave-uniform; lane i lands at lds + i*16.
__device__ inline void glds16(const bf16* g, bf16* lds) {
  __builtin_amdgcn_global_load_lds(
      (const __attribute__((address_space(1))) void*)g,
      (__attribute__((address_space(3))) void*)lds, 16, 0, 0);
}

// rotate bf16x8 left by r elements: out[i] = v[(i+r)&7]. All compile-time vector
// subscripts (runtime subscripts spill to scratch); selects become v_cndmask,
// 1-element stage is v_alignbit.
__device__ inline bf16x8 rot8(bf16x8 v, int r) {
  union U { bf16x8 b; uint32_t d[4]; };
  U u; u.b = v;
  uint32_t e0 = (r & 4) ? u.d[2] : u.d[0], e1 = (r & 4) ? u.d[3] : u.d[1];
  uint32_t e2 = (r & 4) ? u.d[0] : u.d[2], e3 = (r & 4) ? u.d[1] : u.d[3];
  uint32_t f0 = (r & 2) ? e1 : e0, f1 = (r & 2) ? e2 : e1;
  uint32_t f2 = (r & 2) ? e3 : e2, f3 = (r & 2) ? e0 : e3;
  U o;
  o.d[0] = (r & 1) ? __builtin_amdgcn_alignbit(f1, f0, 16) : f0;
  o.d[1] = (r & 1) ? __builtin_amdgcn_alignbit(f2, f1, 16) : f1;
  o.d[2] = (r & 1) ? __builtin_amdgcn_alignbit(f3, f2, 16) : f2;
  o.d[3] = (r & 1) ? __builtin_amdgcn_alignbit(f0, f3, 16) : f3;
  return o.b;
}

// ---------------- small utility kernels ----------------

__global__ void prep_small_kernel(const float* __restrict__ modv, const float* __restrict__ e,
                                  float* __restrict__ e6f,
                                  const float* __restrict__ qb, const float* __restrict__ kb,
                                  const float* __restrict__ vb, float* __restrict__ qkvB,
                                  const float* __restrict__ ckb, const float* __restrict__ cvb,
                                  float* __restrict__ kvB,
                                  const float* __restrict__ kib, const float* __restrict__ vib,
                                  float* __restrict__ kivB) {
  int i = blockIdx.x * 256 + threadIdx.x;
  if (i < 6 * DIM) e6f[i] = modv[i] + e[i];
  if (i < DIM) {
    qkvB[i] = qb[i]; qkvB[i + DIM] = kb[i]; qkvB[i + 2 * DIM] = vb[i];
    kvB[i] = ckb[i]; kvB[i + DIM] = cvb[i];
    kivB[i] = kib[i]; kivB[i + DIM] = vib[i];
  }
}

// context -> bf16: txt rows 257..768 -> ctxt[512], img rows 0..256 -> ctxi[384] zero-padded
__global__ void prep_ctx_kernel(const float* __restrict__ ctx, bf16* __restrict__ ctxt,
                                bf16* __restrict__ ctxi) {
  int i = blockIdx.x * 256 + threadIdx.x;
  if (i < T5 * DIM) ctxt[i] = (bf16)ctx[(size_t)IMG * DIM + i];
  if (i < IMGP * DIM) {
    int r = i / DIM;
    ctxi[i] = (r < IMG) ? (bf16)ctx[i] : (bf16)0.0f;
  }
}

// transpose up to 3 weights W (K x N, f32) -> Wt (N x K, bf16), z selects source/dest slot.
__global__ void transpose_w3_kernel(const float* __restrict__ W0, const float* __restrict__ W1,
                                    const float* __restrict__ W2, bf16* __restrict__ Wt,
                                    int K, int N) {
  __shared__ float tile[32][33];
  const float* W = blockIdx.z == 0 ? W0 : (blockIdx.z == 1 ? W1 : W2);
  bf16* dst = Wt + (size_t)blockIdx.z * K * N;
  int n0 = blockIdx.x * 32, k0 = blockIdx.y * 32;
  int tx = threadIdx.x, ty = threadIdx.y;  // block (32,8)
  for (int i = ty; i < 32; i += 8)
    tile[i][tx] = W[(size_t)(k0 + i) * N + n0 + tx];
  __syncthreads();
  for (int i = ty; i < 32; i += 8)
    dst[(size_t)(n0 + i) * K + k0 + tx] = (bf16)tile[tx][i];
}

// block=256, two-value sum reduction broadcast to all threads
__device__ inline void block_reduce2(float& s1, float& s2) {
  __shared__ float buf[8];
  for (int off = 32; off; off >>= 1) {
    s1 += __shfl_down(s1, off, 64);
    s2 += __shfl_down(s2, off, 64);
  }
  int w = threadIdx.x >> 6;
  if ((threadIdx.x & 63) == 0) { buf[w] = s1; buf[w + 4] = s2; }
  __syncthreads();
  s1 = buf[0] + buf[1] + buf[2] + buf[3];
  s2 = buf[4] + buf[5] + buf[6] + buf[7];
  __syncthreads();
}

// y = LN(x) * (gamma (+1?)) + beta ; one block per row
__global__ __launch_bounds__(256) void ln_mod_kernel(
    const float* __restrict__ X, const float* __restrict__ gamma,
    const float* __restrict__ beta, int plus_one, bf16* __restrict__ out) {
  int r = blockIdx.x;
  const float* xr = X + (size_t)r * DIM;
  float v[6], s = 0.f, s2 = 0.f;
  for (int i = 0; i < 6; i++) {
    v[i] = xr[threadIdx.x + i * 256];
    s += v[i]; s2 += v[i] * v[i];
  }
  block_reduce2(s, s2);
  float mean = s * (1.0f / DIM);
  float var = s2 * (1.0f / DIM) - mean * mean;
  float rstd = rsqrtf(var + EPSL);
  float add1 = plus_one ? 1.0f : 0.0f;
  for (int i = 0; i < 6; i++) {
    int c = threadIdx.x + i * 256;
    out[(size_t)r * DIM + c] = (bf16)(((v[i] - mean) * rstd) * (gamma[c] + add1) + beta[c]);
  }
}

// fused per-row postprocess of a GEMM f32 output with row stride `istride`:
// blockIdx.y = section; per section: mode 0=cast, 1=rms, 2=rms+rope
// s0scale is folded into section-0 output (q pre-scaled by log2e/sqrt(HD) so
// the attention kernel's softmax runs in the exp2 domain with no per-score mul)
__global__ __launch_bounds__(256) void rms_rope_multi_kernel(
    const float* __restrict__ X, int istride, int nsec,
    const float* __restrict__ nw0, const float* __restrict__ nw1,
    int mode0, int mode1, int mode2, float s0scale,
    const float* __restrict__ freqs,
    bf16* __restrict__ o0, bf16* __restrict__ o1, bf16* __restrict__ o2) {
  int sec = blockIdx.y;
  int r = blockIdx.x;
  const float* xr = X + (size_t)r * istride + sec * DIM;
  const float* nw = sec == 0 ? nw0 : nw1;
  bf16* out = (sec == 0 ? o0 : (sec == 1 ? o1 : o2)) + (size_t)r * DIM;
  int mode = sec == 0 ? mode0 : (sec == 1 ? mode1 : mode2);
  float v[6];
  for (int i = 0; i < 6; i++) v[i] = xr[threadIdx.x + i * 256];
  if (mode == 0) {
    for (int i = 0; i < 6; i++) out[threadIdx.x + i * 256] = (bf16)v[i];
    return;
  }
  float s2 = 0.f, dummy = 0.f;
  for (int i = 0; i < 6; i++) s2 += v[i] * v[i];
  block_reduce2(s2, dummy);
  float rms = rsqrtf(s2 * (1.0f / DIM) + EPSL);
  if (sec == 0) rms *= s0scale;
  if (mode == 1) {
    for (int i = 0; i < 6; i++) {
      int c = threadIdx.x + i * 256;
      out[c] = (bf16)(v[i] * rms * nw[c]);
    }
  } else {
    int f = r / (18 * 24), rem = r % (18 * 24), hh = rem / 24, ww = rem % 24;
    for (int i = 0; i < 3; i++) {
      int p = threadIdx.x + i * 256;  // pair index
      int id = p & 63;
      int idx = id < 22 ? f : (id < 43 ? hh : ww);
      float th = freqs[idx * 64 + id];
      float cs = __cosf(th), sn = __sinf(th);
      float re = xr[2 * p] * rms * nw[2 * p];
      float im = xr[2 * p + 1] * rms * nw[2 * p + 1];
      out[2 * p]     = (bf16)(re * cs - im * sn);
      out[2 * p + 1] = (bf16)(re * sn + im * cs);
    }
  }
}

// FFN2 split-K reduce: out = xcur + (p0 + p1 + b2[col]) * e5[col]
__global__ void ffn2_reduce_kernel(const float* __restrict__ p, const float* __restrict__ b2,
                                   const float* __restrict__ e5, const float* __restrict__ xcur,
                                   float* __restrict__ out) {
  int i = blockIdx.x * 256 + threadIdx.x;
  if (i >= SQ * DIM) return;
  int col = i % DIM;
  out[i] = xcur[i] + (p[i] + p[i + (size_t)SQ * DIM] + b2[col]) * e5[col];
}

// ---------------- GEMM: C[M,N] = A[M,K](bf16) @ Wt[N,K]^T + epilogue ----------------
template <int BM>
__global__ __launch_bounds__(256) void gemm_db_kernel(
    const bf16* __restrict__ A, const bf16* __restrict__ Wt,
    const float* __restrict__ bias, const float* __restrict__ scalev,
    const float* __restrict__ resid, float* __restrict__ outF,
    bf16* __restrict__ outB, int M, int N, int K, int gelu, int ksplit) {
  constexpr int MI = BM / 32;
  constexpr int NAW = BM / 64;  // A glds per wave
  __shared__ bf16 As[2][BM * 32];
  __shared__ bf16 Bs[2][128 * 32];
  int tid = threadIdx.x;
  int tm0 = blockIdx.y * BM, tn0 = blockIdx.x * 128;
  int lane = tid & 63, wave = tid >> 6;
  int quad = lane >> 4, l16 = lane & 15;
  int mbase = (wave >> 1) * (BM / 2), nbase = (wave & 1) * 64;
  int lrow = lane >> 2, lcol = (lane & 3) * 8;
  int klen = K / ksplit;
  int kbeg = blockIdx.z * klen;

  const bf16* aP[NAW];
  const bf16* bP[2];
#pragma unroll
  for (int j = 0; j < NAW; j++) {
    int c = wave * NAW + j;
    aP[j] = A + (size_t)(tm0 + c * 16 + lrow) * K + kbeg + lcol;
  }
#pragma unroll
  for (int j = 0; j < 2; j++) {
    int c = wave * 2 + j;
    bP[j] = Wt + (size_t)(tn0 + c * 16 + lrow) * K + kbeg + lcol;
  }

  f32x4 acc[MI][4];
#pragma unroll
  for (int mi = 0; mi < MI; mi++)
    for (int ni = 0; ni < 4; ni++)
      for (int rr = 0; rr < 4; rr++) acc[mi][ni][rr] = 0.0f;

  auto stage = [&](int buf) {
#pragma unroll
    for (int j = 0; j < NAW; j++) {
      glds16(aP[j], &As[buf][(wave * NAW + j) * 512]);
      aP[j] += 32;
    }
#pragma unroll
    for (int j = 0; j < 2; j++) {
      glds16(bP[j], &Bs[buf][(wave * 2 + j) * 512]);
      bP[j] += 32;
    }
  };

  int niter = klen / 32;
  stage(0);
  int cur = 0;
  for (int it = 0; it < niter; it++) {
    __syncthreads();               // drains vmcnt: tile `cur` resident in LDS
    if (it + 1 < niter) stage(cur ^ 1);  // prefetch overlaps compute below
    bf16x8 af[MI], bfr[4];
#pragma unroll
    for (int mi = 0; mi < MI; mi++)
      af[mi] = *(bf16x8*)&As[cur][(mbase + mi * 16 + l16) * 32 + quad * 8];
#pragma unroll
    for (int ni = 0; ni < 4; ni++)
      bfr[ni] = *(bf16x8*)&Bs[cur][(nbase + ni * 16 + l16) * 32 + quad * 8];
#pragma unroll
    for (int mi = 0; mi < MI; mi++)
#pragma unroll
      for (int ni = 0; ni < 4; ni++)
        acc[mi][ni] = __builtin_amdgcn_mfma_f32_16x16x32_bf16(af[mi], bfr[ni], acc[mi][ni], 0, 0, 0);
    cur ^= 1;
  }

  if (ksplit > 1) {
    float* po = outF + (size_t)blockIdx.z * M * N;
#pragma unroll
    for (int mi = 0; mi < MI; mi++) {
      int rbase = tm0 + mbase + mi * 16 + quad * 4;
#pragma unroll
      for (int ni = 0; ni < 4; ni++) {
        int col = tn0 + nbase + ni * 16 + l16;
        for (int rr = 0; rr < 4; rr++)
          po[(size_t)(rbase + rr) * N + col] = acc[mi][ni][rr];
      }
    }
    return;
  }

#pragma unroll
  for (int mi = 0; mi < MI; mi++) {
    int rbase = tm0 + mbase + mi * 16 + quad * 4;
#pragma unroll
    for (int ni = 0; ni < 4; ni++) {
      int col = tn0 + nbase + ni * 16 + l16;
      float b = bias ? bias[col] : 0.0f;
      float sc = scalev ? scalev[col] : 1.0f;
      for (int rr = 0; rr < 4; rr++) {
        int row = rbase + rr;
        float t = acc[mi][ni][rr] + b;
        if (gelu) {
          float z = t;
          float u = 0.7978845608028654f * (z + 0.044715f * z * z * z);
          t = z / (1.0f + __expf(-2.0f * u));  // == 0.5z(1+tanh(u))
        }
        t *= sc;
        size_t idx = (size_t)row * N + col;
        if (resid) t += resid[idx];
        if (outF) outF[idx] = t;
        else outB[idx] = (bf16)t;
      }
    }
  }
}

// ---------------- Flash attention, K-split partials, KVBLK=64 ----------------
// r3-proven structure (rot8 V-transpose, Ps XOR swizzle, ones-MFMA row-sum,
// defer-max ballot) plus this round's safe cuts:
//  - q arrives pre-scaled by log2e/sqrt(HD): softmax in exp2 domain (v_exp_f32
//    is natively 2^x), removing 32 muls per 64-key tile. Threshold 11.54 = 8*log2e.
//  - validity masking hoisted behind a wave-uniform tail-tile branch (img only).
//  - secondary K/V source (Kb2 for bz >= zsplit1) fuses the txt+img cross-attn
//    dispatches into a single launch.
__global__ __launch_bounds__(256) void attn_kernel(
    const bf16* __restrict__ Q, const bf16* __restrict__ Kb, const bf16* __restrict__ Vb,
    const bf16* __restrict__ Kb2, const bf16* __restrict__ Vb2,
    float* __restrict__ Opart, float* __restrict__ mlb,
    int L, int kchunk, int zsplit1, int Lsec, int kchunk2) {
  __shared__ bf16 Ks[64][136];
  __shared__ bf16 Vts[128][72];
  __shared__ bf16 Ps[4][16][72];

  // XCD-contiguity swizzle (bijective when nwg % 8 == 0; all our grids are).
  int nwg = gridDim.x * gridDim.y * gridDim.z;
  int flat = blockIdx.x + gridDim.x * (blockIdx.y + gridDim.y * blockIdx.z);
  if ((nwg & 7) == 0) flat = (flat & 7) * (nwg >> 3) + (flat >> 3);
  int bx = flat % gridDim.x;
  int rest = flat / gridDim.x;
  int hb = rest % gridDim.y;
  int bz = rest / gridDim.y;

  int tid = threadIdx.x;
  int q0 = bx * 64;
  int sec = bz >= zsplit1;
  int bzl = sec ? bz - zsplit1 : bz;
  const bf16* Kp = sec ? Kb2 : Kb;
  const bf16* Vp = sec ? Vb2 : Vb;
  int Lv = sec ? Lsec : L;
  int kch = sec ? kchunk2 : kchunk;
  int kbeg = bzl * kch;
  int kend = min(Lv, kbeg + kch);
  int klen = kend - kbeg;
  int zabs = bz;
  int lane = tid & 63, wave = tid >> 6;
  int quad = lane >> 4, l16 = lane & 15;
  int qrow = q0 + wave * 16 + l16;

  bf16x8 qf[4];
#pragma unroll
  for (int c = 0; c < 4; c++)
    qf[c] = *(const bf16x8*)(Q + (size_t)qrow * DIM + hb * HD + c * 32 + quad * 8);

  bf16x8 onesv;
#pragma unroll
  for (int i = 0; i < 8; i++) onesv[i] = (bf16)1.0f;

  f32x4 o[8];
#pragma unroll
  for (int ff = 0; ff < 8; ff++)
    for (int rr = 0; rr < 4; rr++) o[ff][rr] = 0.0f;
  float m_i[4], l_i[4];
#pragma unroll
  for (int r = 0; r < 4; r++) { m_i[r] = -1e30f; l_i[r] = 0.0f; }

  // staging: 4 threads per key row; each loads 4x16B (32 cols) of K and V
  int srow = tid >> 2, scolc = tid & 3;
  int rot = (2 * scolc + (srow & 1)) & 7;
  int nt = (klen + 63) / 64;
  int tail = (klen & 63) != 0;

  const bf16* kp0 = Kp + (size_t)(kbeg + srow) * DIM + hb * HD + scolc * 8;
  const bf16* vp0 = Vp + (size_t)(kbeg + srow) * DIM + hb * HD + scolc * 8;

  bf16x8 kreg[4], vreg[4];
  if (srow < klen) {
#pragma unroll
    for (int c = 0; c < 4; c++) {
      kreg[c] = *(const bf16x8*)(kp0 + c * 32);
      vreg[c] = *(const bf16x8*)(vp0 + c * 32);
    }
  } else {
#pragma unroll
    for (int c = 0; c < 4; c++) { kreg[c] = zero_bf16x8(); vreg[c] = zero_bf16x8(); }
  }

  for (int kt = 0; kt < nt; kt++) {
    __syncthreads();  // prev tile's LDS readers done
#pragma unroll
    for (int c = 0; c < 4; c++)
      *(bf16x8*)&Ks[srow][scolc * 8 + c * 32] = kreg[c];
#pragma unroll
    for (int c = 0; c < 4; c++) {
      bf16x8 rv = rot8(vreg[c], rot);
      int v0 = scolc * 8 + c * 32;
#pragma unroll
      for (int i = 0; i < 8; i++) {
        int jj = (i + rot) & 7;
        Vts[v0 + jj][srow] = rv[i];
      }
    }
    // prefetch next tile into registers; consumed after next loop-top barrier
    if (kt + 1 < nt) {
      int key = (kt + 1) * 64 + srow;
      const bf16* kp = kp0 + (size_t)(kt + 1) * 64 * DIM;
      const bf16* vp = vp0 + (size_t)(kt + 1) * 64 * DIM;
      if (key < klen) {
#pragma unroll
        for (int c = 0; c < 4; c++) {
          kreg[c] = *(const bf16x8*)(kp + c * 32);
          vreg[c] = *(const bf16x8*)(vp + c * 32);
        }
      } else {
#pragma unroll
        for (int c = 0; c < 4; c++) { kreg[c] = zero_bf16x8(); vreg[c] = zero_bf16x8(); }
      }
    }
    __syncthreads();  // staged tile visible

    f32x4 sfr[4];
    __builtin_amdgcn_s_setprio(1);
#pragma unroll
    for (int nf = 0; nf < 4; nf++) {
      f32x4 a;
      for (int rr = 0; rr < 4; rr++) a[rr] = 0.0f;
#pragma unroll
      for (int c = 0; c < 4; c++) {
        bf16x8 kf = *(bf16x8*)&Ks[nf * 16 + l16][c * 32 + quad * 8];
        a = __builtin_amdgcn_mfma_f32_16x16x32_bf16(qf[c], kf, a, 0, 0, 0);
      }
      sfr[nf] = a;
    }
    __builtin_amdgcn_s_setprio(0);

    if (tail && kt == nt - 1) {  // wave-uniform; only img (257) has a tail
#pragma unroll
      for (int nf = 0; nf < 4; nf++) {
        int colg = kt * 64 + nf * 16 + l16;
        bool valid = colg < klen;
#pragma unroll
        for (int r = 0; r < 4; r++)
          sfr[nf][r] = valid ? sfr[nf][r] : -1e30f;
      }
    }

    // defer-max: local per-lane max + one ballot; full chain only when needed
    float lmax[4];
#pragma unroll
    for (int r = 0; r < 4; r++)
      lmax[r] = fmaxf(fmaxf(sfr[0][r], sfr[1][r]), fmaxf(sfr[2][r], sfr[3][r]));
    int ok = (lmax[0] <= m_i[0] + 11.54f) & (lmax[1] <= m_i[1] + 11.54f) &
             (lmax[2] <= m_i[2] + 11.54f) & (lmax[3] <= m_i[3] + 11.54f);
    if (!__all(ok)) {
#pragma unroll
      for (int r = 0; r < 4; r++) {
        float t = lmax[r];
#pragma unroll
        for (int off = 1; off < 16; off <<= 1) t = fmaxf(t, __shfl_xor(t, off, 64));
        float mnew = fmaxf(m_i[r], t);
        float alpha = exp2f(m_i[r] - mnew);
        m_i[r] = mnew;
        l_i[r] *= alpha;
#pragma unroll
        for (int ff = 0; ff < 8; ff++) o[ff][r] *= alpha;
      }
    }

    // p = 2^(s - m) (bounded by 2^11.54 = e^8), write to Ps with row-XOR swizzle
#pragma unroll
    for (int r = 0; r < 4; r++) {
      char* prow = (char*)&Ps[wave][quad * 4 + r][0];
      int swzW = ((quad >> 1) & 1) << 5;  // f(row)= (row>>3 &1)*32 bytes
#pragma unroll
      for (int nf = 0; nf < 4; nf++) {
        float p = exp2f(sfr[nf][r] - m_i[r]);
        *(bf16*)(prow + (((nf * 16 + l16) * 2) ^ swzW)) = (bf16)p;
      }
    }
    // read P fragments (row = l16 -> XOR key = (l16>>3 &1)*32 bytes)
    int swzR = ((l16 >> 3) & 1) << 5;
    bf16x8 pf[2];
#pragma unroll
    for (int ks = 0; ks < 2; ks++)
      pf[ks] = *(bf16x8*)((char*)&Ps[wave][l16][0] + (((ks * 32 + quad * 8) * 2) ^ swzR));

    __builtin_amdgcn_s_setprio(1);
    // l-sum via MFMA with ones-B: D[row,*] = sum_k P[row,k]; lands in l_i layout
    f32x4 ld;
    for (int rr = 0; rr < 4; rr++) ld[rr] = 0.0f;
    ld = __builtin_amdgcn_mfma_f32_16x16x32_bf16(pf[0], onesv, ld, 0, 0, 0);
    ld = __builtin_amdgcn_mfma_f32_16x16x32_bf16(pf[1], onesv, ld, 0, 0, 0);
#pragma unroll
    for (int ff = 0; ff < 8; ff++) {
#pragma unroll
      for (int ks = 0; ks < 2; ks++) {
        bf16x8 vf = *(bf16x8*)&Vts[ff * 16 + l16][ks * 32 + quad * 8];
        o[ff] = __builtin_amdgcn_mfma_f32_16x16x32_bf16(pf[ks], vf, o[ff], 0, 0, 0);
      }
    }
    __builtin_amdgcn_s_setprio(0);
#pragma unroll
    for (int r = 0; r < 4; r++) l_i[r] += ld[r];
  }

  float* po = Opart + (size_t)zabs * SQ * DIM;
#pragma unroll
  for (int r = 0; r < 4; r++) {
    float inv = 1.0f / l_i[r];
#pragma unroll
    for (int ff = 0; ff < 8; ff++) o[ff][r] *= inv;
  }
#pragma unroll
  for (int ff = 0; ff < 8; ff++) {
#pragma unroll
    for (int r = 0; r < 4; r++) {
      int row = q0 + wave * 16 + quad * 4 + r;
      int col = hb * HD + ff * 16 + l16;
      po[(size_t)row * DIM + col] = o[ff][r];
    }
  }
  if (l16 == 0) {
#pragma unroll
    for (int r = 0; r < 4; r++) {
      int row = q0 + wave * 16 + quad * 4 + r;
      size_t mi = (((size_t)zabs * NHEADS + hb) * SQ + row) * 2;
      mlb[mi] = m_i[r];
      mlb[mi + 1] = l_i[r];
    }
  }
}

// Combine partial attention outputs (m values are in the exp2/log2 domain).
// Slots [0, nmerge) are flash-decoding partials of ONE softmax -> merged with
// weights w_z = l_z*2^(m_z-M)/sum. If addslot >= 0, that slot is a SEPARATE,
// already-normalized attention output that is ADDED (reference cross-attn is
// softmax(txt) + softmax(img), NOT a softmax over the union).
__global__ __launch_bounds__(256) void attn_combine_kernel(
    const float* __restrict__ Op, const float* __restrict__ mlb,
    bf16* __restrict__ out, int nmerge, int addslot) {
  int row = blockIdx.x;
  __shared__ float wsh[3 * NHEADS];
  int t = threadIdx.x;
  if (t < NHEADS) {
    float m[3], l[3];
    for (int z = 0; z < 3; z++) {
      if (z < nmerge) {
        size_t b = (((size_t)z * NHEADS + t) * SQ + row) * 2;
        m[z] = mlb[b]; l[z] = mlb[b + 1];
      } else {
        m[z] = -1e30f; l[z] = 0.0f;
      }
    }
    float M = fmaxf(m[0], fmaxf(m[1], m[2]));
    float w0 = l[0] * exp2f(m[0] - M);
    float w1 = l[1] * exp2f(m[1] - M);
    float w2 = l[2] * exp2f(m[2] - M);
    float inv = 1.0f / (w0 + w1 + w2);
    wsh[t] = w0 * inv;
    wsh[NHEADS + t] = w1 * inv;
    wsh[2 * NHEADS + t] = w2 * inv;
  }
  __syncthreads();
#pragma unroll
  for (int i = 0; i < 6; i++) {
    int c = t + i * 256;
    int h = c >> 7;
    float acc = wsh[h] * Op[((size_t)0 * SQ + row) * DIM + c];
    if (nmerge > 1) acc += wsh[NHEADS + h] * Op[((size_t)1 * SQ + row) * DIM + c];
    if (nmerge > 2) acc += wsh[2 * NHEADS + h] * Op[((size_t)2 * SQ + row) * DIM + c];
    if (addslot >= 0) acc += Op[((size_t)addslot * SQ + row) * DIM + c];
    out[(size_t)row * DIM + c] = (bf16)acc;
  }
}

// ---------------- host orchestration ----------------

extern "C" void kernel_launch(void* const* d_in, const int* in_sizes, int n_in,
                              void* d_out, int out_size, void* d_ws, size_t ws_size,
                              hipStream_t stream) {
  const float* x      = (const float*)d_in[0];
  const float* e      = (const float*)d_in[1];
  const float* ctx    = (const float*)d_in[2];
  const float* freqs  = (const float*)d_in[3];
  const float* modv   = (const float*)d_in[4];
  const float* sa_qw  = (const float*)d_in[5];
  const float* sa_qb  = (const float*)d_in[6];
  const float* sa_kw  = (const float*)d_in[7];
  const float* sa_kb  = (const float*)d_in[8];
  const float* sa_vw  = (const float*)d_in[9];
  const float* sa_vb  = (const float*)d_in[10];
  const float* sa_ow  = (const float*)d_in[11];
  const float* sa_ob  = (const float*)d_in[12];
  const float* sa_nq  = (const float*)d_in[13];
  const float* sa_nk  = (const float*)d_in[14];
  const float* norm3w = (const float*)d_in[15];
  const float* norm3b = (const float*)d_in[16];
  const float* ca_qw  = (const float*)d_in[17];
  const float* ca_qb  = (const float*)d_in[18];
  const float* ca_kw  = (const float*)d_in[19];
  const float* ca_kb  = (const float*)d_in[20];
  const float* ca_vw  = (const float*)d_in[21];
  const float* ca_vb  = (const float*)d_in[22];
  const float* ca_kiw = (const float*)d_in[23];
  const float* ca_kib = (const float*)d_in[24];
  const float* ca_viw = (const float*)d_in[25];
  const float* ca_vib = (const float*)d_in[26];
  const float* ca_ow  = (const float*)d_in[27];
  const float* ca_ob  = (const float*)d_in[28];
  const float* ca_nq  = (const float*)d_in[29];
  const float* ca_nk  = (const float*)d_in[30];
  const float* ca_nki = (const float*)d_in[31];
  const float* ffn_w1 = (const float*)d_in[32];
  const float* ffn_b1 = (const float*)d_in[33];
  const float* ffn_w2 = (const float*)d_in[34];
  const float* ffn_b2 = (const float*)d_in[35];

  char* ws = (char*)d_ws;
  size_t off = 0;
  auto alloc = [&](size_t bytes) -> void* {
    void* p = ws + off;
    off += (bytes + 255) & ~(size_t)255;
    return p;
  };
  float* e6f   = (float*)alloc((size_t)6 * DIM * 4);
  bf16* act_bf = (bf16*)alloc((size_t)SQ * DIM * 2);
  bf16* q_bf   = (bf16*)alloc((size_t)SQ * DIM * 2);
  bf16* k_bf   = (bf16*)alloc((size_t)SQ * DIM * 2);
  bf16* v_bf   = (bf16*)alloc((size_t)SQ * DIM * 2);
  // big0 shared region: qkvF [SQ,4608] f32 -> attn partials [3][SQ,DIM] f32
  //   -> projf [SQ,DIM] f32 -> cross partials -> y1 [SQ,FFN] bf16
  char* big0   = (char*)alloc((size_t)SQ * 3 * DIM * 4);
  float* xcur  = (float*)alloc((size_t)SQ * DIM * 4);
  bf16* wbig   = (bf16*)alloc((size_t)FFN * DIM * 2);     // qkvT / w1T / w2T (sequential reuse)
  bf16* wsm    = (bf16*)alloc((size_t)3 * DIM * DIM * 2); // owT/qT/kvT (sequential reuse)
  bf16* ctxt_bf = (bf16*)alloc((size_t)T5 * DIM * 2);
  bf16* ctxi_bf = (bf16*)alloc((size_t)IMGP * DIM * 2);
  float* ctxkvF = (float*)alloc((size_t)T5 * 2 * DIM * 4);
  float* ctxkivF = (float*)alloc((size_t)IMGP * 2 * DIM * 4);
  bf16* kt_bf  = (bf16*)alloc((size_t)T5 * DIM * 2);
  bf16* vt_bf  = (bf16*)alloc((size_t)T5 * DIM * 2);
  bf16* ki_bf  = (bf16*)alloc((size_t)IMGP * DIM * 2);
  bf16* vi_bf  = (bf16*)alloc((size_t)IMGP * DIM * 2);
  float* qkvB  = (float*)alloc((size_t)3 * DIM * 4);
  float* kvB   = (float*)alloc((size_t)2 * DIM * 4);
  float* kivB  = (float*)alloc((size_t)2 * DIM * 4);
  float* mlbuf = (float*)alloc((size_t)3 * NHEADS * SQ * 2 * 4);

  float* qkvF = (float*)big0;
  float* projf = (float*)big0;
  float* opart = (float*)big0;
  bf16* y1 = (bf16*)big0;
  float* pbuf = (float*)act_bf;  // FFN2 split-K partials (act/q/k/v dead by then)

  const float* e0 = e6f;
  const float* e1 = e6f + DIM;
  const float* e2 = e6f + 2 * DIM;
  const float* e3 = e6f + 3 * DIM;
  const float* e4 = e6f + 4 * DIM;
  const float* e5 = e6f + 5 * DIM;

  // log2(e)/sqrt(HD): q pre-scale putting softmax in the exp2 domain
  const float SCL2 = 0.12751744f;

  dim3 tblk(32, 8);

  prep_small_kernel<<<(6 * DIM + 255) / 256, 256, 0, stream>>>(
      modv, e, e6f, sa_qb, sa_kb, sa_vb, qkvB, ca_kb, ca_vb, kvB, ca_kib, ca_vib, kivB);

  // xs = LN(x)*(1+e1)+e0
  ln_mod_kernel<<<SQ, 256, 0, stream>>>(x, e1, e0, 1, act_bf);

  // ---- self attention: batched QKV ----
  transpose_w3_kernel<<<dim3(48, 48, 3), tblk, 0, stream>>>(sa_qw, sa_kw, sa_vw, wbig, DIM, DIM);
  gemm_db_kernel<128><<<dim3(3 * DIM / 128, SQ / 128), 256, 0, stream>>>(
      act_bf, wbig, qkvB, nullptr, nullptr, qkvF, nullptr, SQ, 3 * DIM, DIM, 0, 1);
  rms_rope_multi_kernel<<<dim3(SQ, 3), 256, 0, stream>>>(
      qkvF, 3 * DIM, 3, sa_nq, sa_nk, 2, 2, 0, SCL2, freqs, q_bf, k_bf, v_bf);

  // K-split flash attention: 3 chunks of 1152 keys -> partials in big0 (qkvF dead)
  attn_kernel<<<dim3(SQ / 64, NHEADS, 3), 256, 0, stream>>>(
      q_bf, k_bf, v_bf, k_bf, v_bf, opart, mlbuf, SQ, SQ / 3, 3, SQ, SQ / 3);
  attn_combine_kernel<<<SQ, 256, 0, stream>>>(opart, mlbuf, act_bf, 3, -1);

  // x = x + (attn @ sa_ow + sa_ob) * e2
  transpose_w3_kernel<<<dim3(48, 48, 1), tblk, 0, stream>>>(sa_ow, nullptr, nullptr, wsm, DIM, DIM);
  gemm_db_kernel<64><<<dim3(DIM / 128, SQ / 64), 256, 0, stream>>>(
      act_bf, wsm, sa_ob, e2, x, xcur, nullptr, SQ, DIM, DIM, 0, 1);

  // ---- cross attention ----
  ln_mod_kernel<<<SQ, 256, 0, stream>>>(xcur, norm3w, norm3b, 0, act_bf);

  transpose_w3_kernel<<<dim3(48, 48, 1), tblk, 0, stream>>>(ca_qw, nullptr, nullptr, wsm, DIM, DIM);
  gemm_db_kernel<64><<<dim3(DIM / 128, SQ / 64), 256, 0, stream>>>(
      act_bf, wsm, ca_qb, nullptr, nullptr, projf, nullptr, SQ, DIM, DIM, 0, 1);
  rms_rope_multi_kernel<<<dim3(SQ, 1), 256, 0, stream>>>(
      projf, DIM, 1, ca_nq, nullptr, 1, 0, 0, SCL2, freqs, q_bf, nullptr, nullptr);

  prep_ctx_kernel<<<(T5 * DIM + 255) / 256, 256, 0, stream>>>(ctx, ctxt_bf, ctxi_bf);

  // txt K||V batched (M=512, N=3072)
  transpose_w3_kernel<<<dim3(48, 48, 2), tblk, 0, stream>>>(ca_kw, ca_vw, nullptr, wsm, DIM, DIM);
  gemm_db_kernel<64><<<dim3(2 * DIM / 128, T5 / 64), 256, 0, stream>>>(
      ctxt_bf, wsm, kvB, nullptr, nullptr, ctxkvF, nullptr, T5, 2 * DIM, DIM, 0, 1);
  rms_rope_multi_kernel<<<dim3(T5, 2), 256, 0, stream>>>(
      ctxkvF, 2 * DIM, 2, ca_nk, nullptr, 1, 0, 0, 1.0f, freqs, kt_bf, vt_bf, nullptr);

  // img KI||VI batched (M=384 padded, N=3072)
  transpose_w3_kernel<<<dim3(48, 48, 2), tblk, 0, stream>>>(ca_kiw, ca_viw, nullptr, wsm, DIM, DIM);
  gemm_db_kernel<64><<<dim3(2 * DIM / 128, IMGP / 64), 256, 0, stream>>>(
      ctxi_bf, wsm, kivB, nullptr, nullptr, ctxkivF, nullptr, IMGP, 2 * DIM, DIM, 0, 1);
  rms_rope_multi_kernel<<<dim3(IMGP, 2), 256, 0, stream>>>(
      ctxkivF, 2 * DIM, 2, ca_nki, nullptr, 1, 0, 0, 1.0f, freqs, ki_bf, vi_bf, nullptr);

  // cross attn, ONE dispatch: bz 0,1 = txt K-chunks (slots 0,1 of txt softmax),
  // bz 2 = img softmax (slot 2). Combine merges 0,1 and ADDS 2.
  attn_kernel<<<dim3(SQ / 64, NHEADS, 3), 256, 0, stream>>>(
      q_bf, kt_bf, vt_bf, ki_bf, vi_bf, opart, mlbuf, T5, T5 / 2, 2, IMG, IMG);
  attn_combine_kernel<<<SQ, 256, 0, stream>>>(opart, mlbuf, act_bf, 2, 2);

  // x = x + attn2 @ ca_ow + ca_ob
  transpose_w3_kernel<<<dim3(48, 48, 1), tblk, 0, stream>>>(ca_ow, nullptr, nullptr, wsm, DIM, DIM);
  gemm_db_kernel<64><<<dim3(DIM / 128, SQ / 64), 256, 0, stream>>>(
      act_bf, wsm, ca_ob, nullptr, xcur, xcur, nullptr, SQ, DIM, DIM, 0, 1);

  // ---- FFN ----
  ln_mod_kernel<<<SQ, 256, 0, stream>>>(xcur, e4, e3, 1, act_bf);

  transpose_w3_kernel<<<dim3(FFN / 32, 48, 1), tblk, 0, stream>>>(ffn_w1, nullptr, nullptr, wbig, DIM, FFN);
  gemm_db_kernel<128><<<dim3(FFN / 128, SQ / 128), 256, 0, stream>>>(
      act_bf, wbig, ffn_b1, nullptr, nullptr, nullptr, y1, SQ, FFN, DIM, 1, 1);

  transpose_w3_kernel<<<dim3(48, FFN / 32, 1), tblk, 0, stream>>>(ffn_w2, nullptr, nullptr, wbig, FFN, DIM);
  gemm_db_kernel<128><<<dim3(DIM / 128, SQ / 128, 2), 256, 0, stream>>>(
      y1, wbig, nullptr, nullptr, nullptr, pbuf, nullptr, SQ, DIM, FFN, 0, 2);
  ffn2_reduce_kernel<<<(SQ * DIM + 255) / 256, 256, 0, stream>>>(
      pbuf, ffn_b2, e5, xcur, (float*)d_out);
}

// Round 7
// 1221.437 us; speedup vs baseline: 1.0186x; 1.0186x over previous
//
#include <hip/hip_runtime.h>
#include <stdint.h>

#define DIM 1536
#define NHEADS 12
#define HD 128
#define FFN 8960
#define SQ 3456
#define T5 512
#define LCTX 769
#define IMG 257
#define IMGP 384
#define EPSL 1e-6f

typedef __bf16 bf16;
typedef __bf16 bf16x8 __attribute__((ext_vector_type(8)));
typedef float f32x4 __attribute__((ext_vector_type(4)));

__device__ inline bf16x8 zero_bf16x8() {
  bf16x8 v;
  for (int i = 0; i < 8; i++) v[i] = (bf16)0.0f;
  return v;
}

// async 16B global -> LDS. lds base must be wave-uniform; lane i lands at lds + i*16.
__device__ inline void glds16(const bf16* g, bf16* lds) {
  __builtin_amdgcn_global_load_lds(
      (const __attribute__((address_space(1))) void*)g,
      (__attribute__((address_space(3))) void*)lds, 16, 0, 0);
}

// ---------------- small utility kernels ----------------

__global__ void prep_small_kernel(const float* __restrict__ modv, const float* __restrict__ e,
                                  float* __restrict__ e6f,
                                  const float* __restrict__ qb, const float* __restrict__ kb,
                                  const float* __restrict__ vb, float* __restrict__ qkvB,
                                  const float* __restrict__ ckb, const float* __restrict__ cvb,
                                  float* __restrict__ kvB,
                                  const float* __restrict__ kib, const float* __restrict__ vib,
                                  float* __restrict__ kivB) {
  int i = blockIdx.x * 256 + threadIdx.x;
  if (i < 6 * DIM) e6f[i] = modv[i] + e[i];
  if (i < DIM) {
    qkvB[i] = qb[i]; qkvB[i + DIM] = kb[i]; qkvB[i + 2 * DIM] = vb[i];
    kvB[i] = ckb[i]; kvB[i + DIM] = cvb[i];
    kivB[i] = kib[i]; kivB[i + DIM] = vib[i];
  }
}

// context -> bf16: txt rows 257..768 -> ctxt[512], img rows 0..256 -> ctxi[384] zero-padded
__global__ void prep_ctx_kernel(const float* __restrict__ ctx, bf16* __restrict__ ctxt,
                                bf16* __restrict__ ctxi) {
  int i = blockIdx.x * 256 + threadIdx.x;
  if (i < T5 * DIM) ctxt[i] = (bf16)ctx[(size_t)IMG * DIM + i];
  if (i < IMGP * DIM) {
    int r = i / DIM;
    ctxi[i] = (r < IMG) ? (bf16)ctx[i] : (bf16)0.0f;
  }
}

// transpose up to 3 weights W (K x N, f32) -> Wt (N x K, bf16), z selects source/dest slot.
__global__ void transpose_w3_kernel(const float* __restrict__ W0, const float* __restrict__ W1,
                                    const float* __restrict__ W2, bf16* __restrict__ Wt,
                                    int K, int N) {
  __shared__ float tile[32][33];
  const float* W = blockIdx.z == 0 ? W0 : (blockIdx.z == 1 ? W1 : W2);
  bf16* dst = Wt + (size_t)blockIdx.z * K * N;
  int n0 = blockIdx.x * 32, k0 = blockIdx.y * 32;
  int tx = threadIdx.x, ty = threadIdx.y;  // block (32,8)
  for (int i = ty; i < 32; i += 8)
    tile[i][tx] = W[(size_t)(k0 + i) * N + n0 + tx];
  __syncthreads();
  for (int i = ty; i < 32; i += 8)
    dst[(size_t)(n0 + i) * K + k0 + tx] = (bf16)tile[tx][i];
}

// block=256, two-value sum reduction broadcast to all threads
__device__ inline void block_reduce2(float& s1, float& s2) {
  __shared__ float buf[8];
  for (int off = 32; off; off >>= 1) {
    s1 += __shfl_down(s1, off, 64);
    s2 += __shfl_down(s2, off, 64);
  }
  int w = threadIdx.x >> 6;
  if ((threadIdx.x & 63) == 0) { buf[w] = s1; buf[w + 4] = s2; }
  __syncthreads();
  s1 = buf[0] + buf[1] + buf[2] + buf[3];
  s2 = buf[4] + buf[5] + buf[6] + buf[7];
  __syncthreads();
}

// y = LN(x) * (gamma (+1?)) + beta ; one block per row
__global__ __launch_bounds__(256) void ln_mod_kernel(
    const float* __restrict__ X, const float* __restrict__ gamma,
    const float* __restrict__ beta, int plus_one, bf16* __restrict__ out) {
  int r = blockIdx.x;
  const float* xr = X + (size_t)r * DIM;
  float v[6], s = 0.f, s2 = 0.f;
  for (int i = 0; i < 6; i++) {
    v[i] = xr[threadIdx.x + i * 256];
    s += v[i]; s2 += v[i] * v[i];
  }
  block_reduce2(s, s2);
  float mean = s * (1.0f / DIM);
  float var = s2 * (1.0f / DIM) - mean * mean;
  float rstd = rsqrtf(var + EPSL);
  float add1 = plus_one ? 1.0f : 0.0f;
  for (int i = 0; i < 6; i++) {
    int c = threadIdx.x + i * 256;
    out[(size_t)r * DIM + c] = (bf16)(((v[i] - mean) * rstd) * (gamma[c] + add1) + beta[c]);
  }
}

// fused per-row postprocess of a GEMM f32 output with row stride `istride`:
// blockIdx.y = section; per section: mode 0=cast, 1=rms, 2=rms+rope
// s0scale is folded into section-0 output (q pre-scaled by log2e/sqrt(HD) so
// the attention kernel's softmax runs in the exp2 domain with no per-score mul)
__global__ __launch_bounds__(256) void rms_rope_multi_kernel(
    const float* __restrict__ X, int istride, int nsec,
    const float* __restrict__ nw0, const float* __restrict__ nw1,
    int mode0, int mode1, int mode2, float s0scale,
    const float* __restrict__ freqs,
    bf16* __restrict__ o0, bf16* __restrict__ o1, bf16* __restrict__ o2) {
  int sec = blockIdx.y;
  int r = blockIdx.x;
  const float* xr = X + (size_t)r * istride + sec * DIM;
  const float* nw = sec == 0 ? nw0 : nw1;
  bf16* out = (sec == 0 ? o0 : (sec == 1 ? o1 : o2)) + (size_t)r * DIM;
  int mode = sec == 0 ? mode0 : (sec == 1 ? mode1 : mode2);
  float v[6];
  for (int i = 0; i < 6; i++) v[i] = xr[threadIdx.x + i * 256];
  if (mode == 0) {
    for (int i = 0; i < 6; i++) out[threadIdx.x + i * 256] = (bf16)v[i];
    return;
  }
  float s2 = 0.f, dummy = 0.f;
  for (int i = 0; i < 6; i++) s2 += v[i] * v[i];
  block_reduce2(s2, dummy);
  float rms = rsqrtf(s2 * (1.0f / DIM) + EPSL);
  if (sec == 0) rms *= s0scale;
  if (mode == 1) {
    for (int i = 0; i < 6; i++) {
      int c = threadIdx.x + i * 256;
      out[c] = (bf16)(v[i] * rms * nw[c]);
    }
  } else {
    int f = r / (18 * 24), rem = r % (18 * 24), hh = rem / 24, ww = rem % 24;
    for (int i = 0; i < 3; i++) {
      int p = threadIdx.x + i * 256;  // pair index
      int id = p & 63;
      int idx = id < 22 ? f : (id < 43 ? hh : ww);
      float th = freqs[idx * 64 + id];
      float cs = __cosf(th), sn = __sinf(th);
      float re = xr[2 * p] * rms * nw[2 * p];
      float im = xr[2 * p + 1] * rms * nw[2 * p + 1];
      out[2 * p]     = (bf16)(re * cs - im * sn);
      out[2 * p + 1] = (bf16)(re * sn + im * cs);
    }
  }
}

// FFN2 split-K reduce: out = xcur + (p0 + p1 + b2[col]) * e5[col]
__global__ void ffn2_reduce_kernel(const float* __restrict__ p, const float* __restrict__ b2,
                                   const float* __restrict__ e5, const float* __restrict__ xcur,
                                   float* __restrict__ out) {
  int i = blockIdx.x * 256 + threadIdx.x;
  if (i >= SQ * DIM) return;
  int col = i % DIM;
  out[i] = xcur[i] + (p[i] + p[i + (size_t)SQ * DIM] + b2[col]) * e5[col];
}

// ---------------- GEMM: C[M,N] = A[M,K](bf16) @ Wt[N,K]^T + epilogue ----------------
template <int BM>
__global__ __launch_bounds__(256) void gemm_db_kernel(
    const bf16* __restrict__ A, const bf16* __restrict__ Wt,
    const float* __restrict__ bias, const float* __restrict__ scalev,
    const float* __restrict__ resid, float* __restrict__ outF,
    bf16* __restrict__ outB, int M, int N, int K, int gelu, int ksplit) {
  constexpr int MI = BM / 32;
  constexpr int NAW = BM / 64;  // A glds per wave
  __shared__ bf16 As[2][BM * 32];
  __shared__ bf16 Bs[2][128 * 32];
  int tid = threadIdx.x;
  int tm0 = blockIdx.y * BM, tn0 = blockIdx.x * 128;
  int lane = tid & 63, wave = tid >> 6;
  int quad = lane >> 4, l16 = lane & 15;
  int mbase = (wave >> 1) * (BM / 2), nbase = (wave & 1) * 64;
  int lrow = lane >> 2, lcol = (lane & 3) * 8;
  int klen = K / ksplit;
  int kbeg = blockIdx.z * klen;

  const bf16* aP[NAW];
  const bf16* bP[2];
#pragma unroll
  for (int j = 0; j < NAW; j++) {
    int c = wave * NAW + j;
    aP[j] = A + (size_t)(tm0 + c * 16 + lrow) * K + kbeg + lcol;
  }
#pragma unroll
  for (int j = 0; j < 2; j++) {
    int c = wave * 2 + j;
    bP[j] = Wt + (size_t)(tn0 + c * 16 + lrow) * K + kbeg + lcol;
  }

  f32x4 acc[MI][4];
#pragma unroll
  for (int mi = 0; mi < MI; mi++)
    for (int ni = 0; ni < 4; ni++)
      for (int rr = 0; rr < 4; rr++) acc[mi][ni][rr] = 0.0f;

  auto stage = [&](int buf) {
#pragma unroll
    for (int j = 0; j < NAW; j++) {
      glds16(aP[j], &As[buf][(wave * NAW + j) * 512]);
      aP[j] += 32;
    }
#pragma unroll
    for (int j = 0; j < 2; j++) {
      glds16(bP[j], &Bs[buf][(wave * 2 + j) * 512]);
      bP[j] += 32;
    }
  };

  int niter = klen / 32;
  stage(0);
  int cur = 0;
  for (int it = 0; it < niter; it++) {
    __syncthreads();               // drains vmcnt: tile `cur` resident in LDS
    if (it + 1 < niter) stage(cur ^ 1);  // prefetch overlaps compute below
    bf16x8 af[MI], bfr[4];
#pragma unroll
    for (int mi = 0; mi < MI; mi++)
      af[mi] = *(bf16x8*)&As[cur][(mbase + mi * 16 + l16) * 32 + quad * 8];
#pragma unroll
    for (int ni = 0; ni < 4; ni++)
      bfr[ni] = *(bf16x8*)&Bs[cur][(nbase + ni * 16 + l16) * 32 + quad * 8];
#pragma unroll
    for (int mi = 0; mi < MI; mi++)
#pragma unroll
      for (int ni = 0; ni < 4; ni++)
        acc[mi][ni] = __builtin_amdgcn_mfma_f32_16x16x32_bf16(af[mi], bfr[ni], acc[mi][ni], 0, 0, 0);
    cur ^= 1;
  }

  if (ksplit > 1) {
    float* po = outF + (size_t)blockIdx.z * M * N;
#pragma unroll
    for (int mi = 0; mi < MI; mi++) {
      int rbase = tm0 + mbase + mi * 16 + quad * 4;
#pragma unroll
      for (int ni = 0; ni < 4; ni++) {
        int col = tn0 + nbase + ni * 16 + l16;
        for (int rr = 0; rr < 4; rr++)
          po[(size_t)(rbase + rr) * N + col] = acc[mi][ni][rr];
      }
    }
    return;
  }

#pragma unroll
  for (int mi = 0; mi < MI; mi++) {
    int rbase = tm0 + mbase + mi * 16 + quad * 4;
#pragma unroll
    for (int ni = 0; ni < 4; ni++) {
      int col = tn0 + nbase + ni * 16 + l16;
      float b = bias ? bias[col] : 0.0f;
      float sc = scalev ? scalev[col] : 1.0f;
      for (int rr = 0; rr < 4; rr++) {
        int row = rbase + rr;
        float t = acc[mi][ni][rr] + b;
        if (gelu) {
          float z = t;
          float u = 0.7978845608028654f * (z + 0.044715f * z * z * z);
          t = z / (1.0f + __expf(-2.0f * u));  // == 0.5z(1+tanh(u))
        }
        t *= sc;
        size_t idx = (size_t)row * N + col;
        if (resid) t += resid[idx];
        if (outF) outF[idx] = t;
        else outB[idx] = (bf16)t;
      }
    }
  }
}

// ---------------- Flash attention, K-split partials, KVBLK=64 ----------------
// k-axis permutation trick: P and V are only contracted against each other over
// k, so both are stored with keys permuted by pi(nf*16+l16) = 4*l16+nf. This
// makes each lane's 4 softmax values CONTIGUOUS in Ps (one ds_write_b64 per
// q-row, replacing 16 scalar writes) and makes the two keys {k, k+16} owned by
// one V-staging thread pi-adjacent (16 packed u32 ds_write_b32 with offset
// immediates, replacing the rot8 networks + 32 scalar b16 writes). QK^T,
// masking, defer-max, the ones-MFMA l-sum and all b128 reads are mechanically
// unchanged. Bank math: V writes hit banks 4j+2*l16+h (all 32, 2 lanes each);
// Ps b64 writes cover all 32 banks exactly 4 dwords each — both at the minimum.
__global__ __launch_bounds__(256) void attn_kernel(
    const bf16* __restrict__ Q, const bf16* __restrict__ Kb, const bf16* __restrict__ Vb,
    const bf16* __restrict__ Kb2, const bf16* __restrict__ Vb2,
    float* __restrict__ Opart, float* __restrict__ mlb,
    int L, int kchunk, int zsplit1, int Lsec, int kchunk2) {
  __shared__ __align__(16) bf16 Ks[64][136];
  __shared__ __align__(16) bf16 Vts[128][72];   // [d][pi(key)] rows 144 B
  __shared__ __align__(16) bf16 Ps[4][16][72];  // [wave][q-row][pi(key)] rows 144 B

  // XCD-contiguity swizzle (bijective when nwg % 8 == 0; all our grids are).
  int nwg = gridDim.x * gridDim.y * gridDim.z;
  int flat = blockIdx.x + gridDim.x * (blockIdx.y + gridDim.y * blockIdx.z);
  if ((nwg & 7) == 0) flat = (flat & 7) * (nwg >> 3) + (flat >> 3);
  int bx = flat % gridDim.x;
  int rest = flat / gridDim.x;
  int hb = rest % gridDim.y;
  int bz = rest / gridDim.y;

  int tid = threadIdx.x;
  int q0 = bx * 64;
  int sec = bz >= zsplit1;
  int bzl = sec ? bz - zsplit1 : bz;
  const bf16* Kp = sec ? Kb2 : Kb;
  const bf16* Vp = sec ? Vb2 : Vb;
  int Lv = sec ? Lsec : L;
  int kch = sec ? kchunk2 : kchunk;
  int kbeg = bzl * kch;
  int kend = min(Lv, kbeg + kch);
  int klen = kend - kbeg;
  int zabs = bz;
  int lane = tid & 63, wave = tid >> 6;
  int quad = lane >> 4, l16 = lane & 15;
  int qrow = q0 + wave * 16 + l16;

  bf16x8 qf[4];
#pragma unroll
  for (int c = 0; c < 4; c++)
    qf[c] = *(const bf16x8*)(Q + (size_t)qrow * DIM + hb * HD + c * 32 + quad * 8);

  bf16x8 onesv;
#pragma unroll
  for (int i = 0; i < 8; i++) onesv[i] = (bf16)1.0f;

  f32x4 o[8];
#pragma unroll
  for (int ff = 0; ff < 8; ff++)
    for (int rr = 0; rr < 4; rr++) o[ff][rr] = 0.0f;
  float m_i[4], l_i[4];
#pragma unroll
  for (int r = 0; r < 4; r++) { m_i[r] = -1e30f; l_i[r] = 0.0f; }

  // K staging: 4 threads per key row; each loads 4x16B (32 cols)
  int srow = tid >> 2, scolc = tid & 3;
  // V staging: thread (vdg, vl, vh) owns keys {vh*32+vl, +16}, d-cols vdg*16..+15
  int vdg = tid >> 5, vl = (tid >> 1) & 15, vh = tid & 1;
  int nt = (klen + 63) / 64;
  int tail = (klen & 63) != 0;

  const bf16* kp0 = Kp + (size_t)(kbeg + srow) * DIM + hb * HD + scolc * 8;
  const bf16* vp0 = Vp + (size_t)(kbeg + vh * 32 + vl) * DIM + hb * HD + vdg * 16;
  // V write base: byte (vdg*16+j)*144 + pi-position (4*vl+2*vh)*2
  char* vwp = (char*)&Vts[0][0] + vdg * (16 * 144) + (4 * vl + 2 * vh) * 2;

  bf16x8 kreg[4], vreg[4];
  if (srow < klen) {
#pragma unroll
    for (int c = 0; c < 4; c++) kreg[c] = *(const bf16x8*)(kp0 + c * 32);
  } else {
#pragma unroll
    for (int c = 0; c < 4; c++) kreg[c] = zero_bf16x8();
  }
  if (vh * 32 + vl < klen) {
    vreg[0] = *(const bf16x8*)vp0;
    vreg[1] = *(const bf16x8*)(vp0 + 8);
  } else { vreg[0] = zero_bf16x8(); vreg[1] = zero_bf16x8(); }
  if (vh * 32 + vl + 16 < klen) {
    vreg[2] = *(const bf16x8*)(vp0 + 16 * DIM);
    vreg[3] = *(const bf16x8*)(vp0 + 16 * DIM + 8);
  } else { vreg[2] = zero_bf16x8(); vreg[3] = zero_bf16x8(); }

  for (int kt = 0; kt < nt; kt++) {
    __syncthreads();  // prev tile's LDS readers done
#pragma unroll
    for (int c = 0; c < 4; c++)
      *(bf16x8*)&Ks[srow][scolc * 8 + c * 32] = kreg[c];
    {
      union U8 { bf16x8 v; uint32_t w[4]; };
      U8 a0, a1, b0, b1;
      a0.v = vreg[0]; a1.v = vreg[1]; b0.v = vreg[2]; b1.v = vreg[3];
#pragma unroll
      for (int j = 0; j < 16; j++) {
        uint32_t w0 = (j < 8) ? a0.w[(j & 7) >> 1] : a1.w[(j & 7) >> 1];
        uint32_t w1 = (j < 8) ? b0.w[(j & 7) >> 1] : b1.w[(j & 7) >> 1];
        uint32_t pk = (j & 1) ? ((w0 >> 16) | (w1 & 0xFFFF0000u))
                              : ((w0 & 0xFFFFu) | (w1 << 16));
        *(uint32_t*)(vwp + j * 144) = pk;
      }
    }
    // prefetch next tile into registers; consumed after next loop-top barrier
    if (kt + 1 < nt) {
      int kb64 = (kt + 1) * 64;
      const bf16* kp = kp0 + (size_t)(kt + 1) * 64 * DIM;
      const bf16* vp = vp0 + (size_t)(kt + 1) * 64 * DIM;
      if (kb64 + srow < klen) {
#pragma unroll
        for (int c = 0; c < 4; c++) kreg[c] = *(const bf16x8*)(kp + c * 32);
      } else {
#pragma unroll
        for (int c = 0; c < 4; c++) kreg[c] = zero_bf16x8();
      }
      if (kb64 + vh * 32 + vl < klen) {
        vreg[0] = *(const bf16x8*)vp;
        vreg[1] = *(const bf16x8*)(vp + 8);
      } else { vreg[0] = zero_bf16x8(); vreg[1] = zero_bf16x8(); }
      if (kb64 + vh * 32 + vl + 16 < klen) {
        vreg[2] = *(const bf16x8*)(vp + 16 * DIM);
        vreg[3] = *(const bf16x8*)(vp + 16 * DIM + 8);
      } else { vreg[2] = zero_bf16x8(); vreg[3] = zero_bf16x8(); }
    }
    __syncthreads();  // staged tile visible

    f32x4 sfr[4];
    __builtin_amdgcn_s_setprio(1);
#pragma unroll
    for (int nf = 0; nf < 4; nf++) {
      f32x4 a;
      for (int rr = 0; rr < 4; rr++) a[rr] = 0.0f;
#pragma unroll
      for (int c = 0; c < 4; c++) {
        bf16x8 kf = *(bf16x8*)&Ks[nf * 16 + l16][c * 32 + quad * 8];
        a = __builtin_amdgcn_mfma_f32_16x16x32_bf16(qf[c], kf, a, 0, 0, 0);
      }
      sfr[nf] = a;
    }
    __builtin_amdgcn_s_setprio(0);

    if (tail && kt == nt - 1) {  // wave-uniform; only img (257) has a tail
#pragma unroll
      for (int nf = 0; nf < 4; nf++) {
        int colg = kt * 64 + nf * 16 + l16;
        bool valid = colg < klen;
#pragma unroll
        for (int r = 0; r < 4; r++)
          sfr[nf][r] = valid ? sfr[nf][r] : -1e30f;
      }
    }

    // defer-max: local per-lane max + one ballot; full chain only when needed
    float lmax[4];
#pragma unroll
    for (int r = 0; r < 4; r++)
      lmax[r] = fmaxf(fmaxf(sfr[0][r], sfr[1][r]), fmaxf(sfr[2][r], sfr[3][r]));
    int ok = (lmax[0] <= m_i[0] + 11.54f) & (lmax[1] <= m_i[1] + 11.54f) &
             (lmax[2] <= m_i[2] + 11.54f) & (lmax[3] <= m_i[3] + 11.54f);
    if (!__all(ok)) {
#pragma unroll
      for (int r = 0; r < 4; r++) {
        float t = lmax[r];
#pragma unroll
        for (int off = 1; off < 16; off <<= 1) t = fmaxf(t, __shfl_xor(t, off, 64));
        float mnew = fmaxf(m_i[r], t);
        float alpha = exp2f(m_i[r] - mnew);
        m_i[r] = mnew;
        l_i[r] *= alpha;
#pragma unroll
        for (int ff = 0; ff < 8; ff++) o[ff][r] *= alpha;
      }
    }

    // p = 2^(s - m); the lane's 4 values are pi-contiguous -> one b64 write/row
#pragma unroll
    for (int r = 0; r < 4; r++) {
      union { bf16 b[4]; unsigned long long u; } pk;
      pk.b[0] = (bf16)exp2f(sfr[0][r] - m_i[r]);
      pk.b[1] = (bf16)exp2f(sfr[1][r] - m_i[r]);
      pk.b[2] = (bf16)exp2f(sfr[2][r] - m_i[r]);
      pk.b[3] = (bf16)exp2f(sfr[3][r] - m_i[r]);
      *(unsigned long long*)((char*)&Ps[wave][quad * 4 + r][0] + l16 * 8) = pk.u;
    }
    // read P fragments (pi-ordered, contiguous b128)
    bf16x8 pf[2];
#pragma unroll
    for (int ks = 0; ks < 2; ks++)
      pf[ks] = *(bf16x8*)&Ps[wave][l16][ks * 32 + quad * 8];

    __builtin_amdgcn_s_setprio(1);
    // l-sum via MFMA with ones-B: D[row,*] = sum_k P[row,k]; lands in l_i layout
    f32x4 ld;
    for (int rr = 0; rr < 4; rr++) ld[rr] = 0.0f;
    ld = __builtin_amdgcn_mfma_f32_16x16x32_bf16(pf[0], onesv, ld, 0, 0, 0);
    ld = __builtin_amdgcn_mfma_f32_16x16x32_bf16(pf[1], onesv, ld, 0, 0, 0);
#pragma unroll
    for (int ff = 0; ff < 8; ff++) {
#pragma unroll
      for (int ks = 0; ks < 2; ks++) {
        bf16x8 vf = *(bf16x8*)&Vts[ff * 16 + l16][ks * 32 + quad * 8];
        o[ff] = __builtin_amdgcn_mfma_f32_16x16x32_bf16(pf[ks], vf, o[ff], 0, 0, 0);
      }
    }
    __builtin_amdgcn_s_setprio(0);
#pragma unroll
    for (int r = 0; r < 4; r++) l_i[r] += ld[r];
  }

  float* po = Opart + (size_t)zabs * SQ * DIM;
#pragma unroll
  for (int r = 0; r < 4; r++) {
    float inv = 1.0f / l_i[r];
#pragma unroll
    for (int ff = 0; ff < 8; ff++) o[ff][r] *= inv;
  }
#pragma unroll
  for (int ff = 0; ff < 8; ff++) {
#pragma unroll
    for (int r = 0; r < 4; r++) {
      int row = q0 + wave * 16 + quad * 4 + r;
      int col = hb * HD + ff * 16 + l16;
      po[(size_t)row * DIM + col] = o[ff][r];
    }
  }
  if (l16 == 0) {
#pragma unroll
    for (int r = 0; r < 4; r++) {
      int row = q0 + wave * 16 + quad * 4 + r;
      size_t mi = (((size_t)zabs * NHEADS + hb) * SQ + row) * 2;
      mlb[mi] = m_i[r];
      mlb[mi + 1] = l_i[r];
    }
  }
}

// Combine partial attention outputs (m values are in the exp2/log2 domain).
// Slots [0, nmerge) are flash-decoding partials of ONE softmax -> merged with
// weights w_z = l_z*2^(m_z-M)/sum. If addslot >= 0, that slot is a SEPARATE,
// already-normalized attention output that is ADDED (reference cross-attn is
// softmax(txt) + softmax(img), NOT a softmax over the union).
__global__ __launch_bounds__(256) void attn_combine_kernel(
    const float* __restrict__ Op, const float* __restrict__ mlb,
    bf16* __restrict__ out, int nmerge, int addslot) {
  int row = blockIdx.x;
  __shared__ float wsh[3 * NHEADS];
  int t = threadIdx.x;
  if (t < NHEADS) {
    float m[3], l[3];
    for (int z = 0; z < 3; z++) {
      if (z < nmerge) {
        size_t b = (((size_t)z * NHEADS + t) * SQ + row) * 2;
        m[z] = mlb[b]; l[z] = mlb[b + 1];
      } else {
        m[z] = -1e30f; l[z] = 0.0f;
      }
    }
    float M = fmaxf(m[0], fmaxf(m[1], m[2]));
    float w0 = l[0] * exp2f(m[0] - M);
    float w1 = l[1] * exp2f(m[1] - M);
    float w2 = l[2] * exp2f(m[2] - M);
    float inv = 1.0f / (w0 + w1 + w2);
    wsh[t] = w0 * inv;
    wsh[NHEADS + t] = w1 * inv;
    wsh[2 * NHEADS + t] = w2 * inv;
  }
  __syncthreads();
#pragma unroll
  for (int i = 0; i < 6; i++) {
    int c = t + i * 256;
    int h = c >> 7;
    float acc = wsh[h] * Op[((size_t)0 * SQ + row) * DIM + c];
    if (nmerge > 1) acc += wsh[NHEADS + h] * Op[((size_t)1 * SQ + row) * DIM + c];
    if (nmerge > 2) acc += wsh[2 * NHEADS + h] * Op[((size_t)2 * SQ + row) * DIM + c];
    if (addslot >= 0) acc += Op[((size_t)addslot * SQ + row) * DIM + c];
    out[(size_t)row * DIM + c] = (bf16)acc;
  }
}

// ---------------- host orchestration ----------------

extern "C" void kernel_launch(void* const* d_in, const int* in_sizes, int n_in,
                              void* d_out, int out_size, void* d_ws, size_t ws_size,
                              hipStream_t stream) {
  const float* x      = (const float*)d_in[0];
  const float* e      = (const float*)d_in[1];
  const float* ctx    = (const float*)d_in[2];
  const float* freqs  = (const float*)d_in[3];
  const float* modv   = (const float*)d_in[4];
  const float* sa_qw  = (const float*)d_in[5];
  const float* sa_qb  = (const float*)d_in[6];
  const float* sa_kw  = (const float*)d_in[7];
  const float* sa_kb  = (const float*)d_in[8];
  const float* sa_vw  = (const float*)d_in[9];
  const float* sa_vb  = (const float*)d_in[10];
  const float* sa_ow  = (const float*)d_in[11];
  const float* sa_ob  = (const float*)d_in[12];
  const float* sa_nq  = (const float*)d_in[13];
  const float* sa_nk  = (const float*)d_in[14];
  const float* norm3w = (const float*)d_in[15];
  const float* norm3b = (const float*)d_in[16];
  const float* ca_qw  = (const float*)d_in[17];
  const float* ca_qb  = (const float*)d_in[18];
  const float* ca_kw  = (const float*)d_in[19];
  const float* ca_kb  = (const float*)d_in[20];
  const float* ca_vw  = (const float*)d_in[21];
  const float* ca_vb  = (const float*)d_in[22];
  const float* ca_kiw = (const float*)d_in[23];
  const float* ca_kib = (const float*)d_in[24];
  const float* ca_viw = (const float*)d_in[25];
  const float* ca_vib = (const float*)d_in[26];
  const float* ca_ow  = (const float*)d_in[27];
  const float* ca_ob  = (const float*)d_in[28];
  const float* ca_nq  = (const float*)d_in[29];
  const float* ca_nk  = (const float*)d_in[30];
  const float* ca_nki = (const float*)d_in[31];
  const float* ffn_w1 = (const float*)d_in[32];
  const float* ffn_b1 = (const float*)d_in[33];
  const float* ffn_w2 = (const float*)d_in[34];
  const float* ffn_b2 = (const float*)d_in[35];

  char* ws = (char*)d_ws;
  size_t off = 0;
  auto alloc = [&](size_t bytes) -> void* {
    void* p = ws + off;
    off += (bytes + 255) & ~(size_t)255;
    return p;
  };
  float* e6f   = (float*)alloc((size_t)6 * DIM * 4);
  bf16* act_bf = (bf16*)alloc((size_t)SQ * DIM * 2);
  bf16* q_bf   = (bf16*)alloc((size_t)SQ * DIM * 2);
  bf16* k_bf   = (bf16*)alloc((size_t)SQ * DIM * 2);
  bf16* v_bf   = (bf16*)alloc((size_t)SQ * DIM * 2);
  // big0 shared region: qkvF [SQ,4608] f32 -> attn partials [3][SQ,DIM] f32
  //   -> projf [SQ,DIM] f32 -> cross partials -> y1 [SQ,FFN] bf16
  char* big0   = (char*)alloc((size_t)SQ * 3 * DIM * 4);
  float* xcur  = (float*)alloc((size_t)SQ * DIM * 4);
  bf16* wbig   = (bf16*)alloc((size_t)FFN * DIM * 2);     // qkvT / w1T / w2T (sequential reuse)
  bf16* wsm    = (bf16*)alloc((size_t)3 * DIM * DIM * 2); // owT/qT/kvT (sequential reuse)
  bf16* ctxt_bf = (bf16*)alloc((size_t)T5 * DIM * 2);
  bf16* ctxi_bf = (bf16*)alloc((size_t)IMGP * DIM * 2);
  float* ctxkvF = (float*)alloc((size_t)T5 * 2 * DIM * 4);
  float* ctxkivF = (float*)alloc((size_t)IMGP * 2 * DIM * 4);
  bf16* kt_bf  = (bf16*)alloc((size_t)T5 * DIM * 2);
  bf16* vt_bf  = (bf16*)alloc((size_t)T5 * DIM * 2);
  bf16* ki_bf  = (bf16*)alloc((size_t)IMGP * DIM * 2);
  bf16* vi_bf  = (bf16*)alloc((size_t)IMGP * DIM * 2);
  float* qkvB  = (float*)alloc((size_t)3 * DIM * 4);
  float* kvB   = (float*)alloc((size_t)2 * DIM * 4);
  float* kivB  = (float*)alloc((size_t)2 * DIM * 4);
  float* mlbuf = (float*)alloc((size_t)3 * NHEADS * SQ * 2 * 4);

  float* qkvF = (float*)big0;
  float* projf = (float*)big0;
  float* opart = (float*)big0;
  bf16* y1 = (bf16*)big0;
  float* pbuf = (float*)act_bf;  // FFN2 split-K partials (act/q/k/v dead by then)

  const float* e0 = e6f;
  const float* e1 = e6f + DIM;
  const float* e2 = e6f + 2 * DIM;
  const float* e3 = e6f + 3 * DIM;
  const float* e4 = e6f + 4 * DIM;
  const float* e5 = e6f + 5 * DIM;

  // log2(e)/sqrt(HD): q pre-scale putting softmax in the exp2 domain
  const float SCL2 = 0.12751744f;

  dim3 tblk(32, 8);

  prep_small_kernel<<<(6 * DIM + 255) / 256, 256, 0, stream>>>(
      modv, e, e6f, sa_qb, sa_kb, sa_vb, qkvB, ca_kb, ca_vb, kvB, ca_kib, ca_vib, kivB);

  // xs = LN(x)*(1+e1)+e0
  ln_mod_kernel<<<SQ, 256, 0, stream>>>(x, e1, e0, 1, act_bf);

  // ---- self attention: batched QKV ----
  transpose_w3_kernel<<<dim3(48, 48, 3), tblk, 0, stream>>>(sa_qw, sa_kw, sa_vw, wbig, DIM, DIM);
  gemm_db_kernel<128><<<dim3(3 * DIM / 128, SQ / 128), 256, 0, stream>>>(
      act_bf, wbig, qkvB, nullptr, nullptr, qkvF, nullptr, SQ, 3 * DIM, DIM, 0, 1);
  rms_rope_multi_kernel<<<dim3(SQ, 3), 256, 0, stream>>>(
      qkvF, 3 * DIM, 3, sa_nq, sa_nk, 2, 2, 0, SCL2, freqs, q_bf, k_bf, v_bf);

  // K-split flash attention: 3 chunks of 1152 keys -> partials in big0 (qkvF dead)
  attn_kernel<<<dim3(SQ / 64, NHEADS, 3), 256, 0, stream>>>(
      q_bf, k_bf, v_bf, k_bf, v_bf, opart, mlbuf, SQ, SQ / 3, 3, SQ, SQ / 3);
  attn_combine_kernel<<<SQ, 256, 0, stream>>>(opart, mlbuf, act_bf, 3, -1);

  // x = x + (attn @ sa_ow + sa_ob) * e2
  transpose_w3_kernel<<<dim3(48, 48, 1), tblk, 0, stream>>>(sa_ow, nullptr, nullptr, wsm, DIM, DIM);
  gemm_db_kernel<64><<<dim3(DIM / 128, SQ / 64), 256, 0, stream>>>(
      act_bf, wsm, sa_ob, e2, x, xcur, nullptr, SQ, DIM, DIM, 0, 1);

  // ---- cross attention ----
  ln_mod_kernel<<<SQ, 256, 0, stream>>>(xcur, norm3w, norm3b, 0, act_bf);

  transpose_w3_kernel<<<dim3(48, 48, 1), tblk, 0, stream>>>(ca_qw, nullptr, nullptr, wsm, DIM, DIM);
  gemm_db_kernel<64><<<dim3(DIM / 128, SQ / 64), 256, 0, stream>>>(
      act_bf, wsm, ca_qb, nullptr, nullptr, projf, nullptr, SQ, DIM, DIM, 0, 1);
  rms_rope_multi_kernel<<<dim3(SQ, 1), 256, 0, stream>>>(
      projf, DIM, 1, ca_nq, nullptr, 1, 0, 0, SCL2, freqs, q_bf, nullptr, nullptr);

  prep_ctx_kernel<<<(T5 * DIM + 255) / 256, 256, 0, stream>>>(ctx, ctxt_bf, ctxi_bf);

  // txt K||V batched (M=512, N=3072)
  transpose_w3_kernel<<<dim3(48, 48, 2), tblk, 0, stream>>>(ca_kw, ca_vw, nullptr, wsm, DIM, DIM);
  gemm_db_kernel<64><<<dim3(2 * DIM / 128, T5 / 64), 256, 0, stream>>>(
      ctxt_bf, wsm, kvB, nullptr, nullptr, ctxkvF, nullptr, T5, 2 * DIM, DIM, 0, 1);
  rms_rope_multi_kernel<<<dim3(T5, 2), 256, 0, stream>>>(
      ctxkvF, 2 * DIM, 2, ca_nk, nullptr, 1, 0, 0, 1.0f, freqs, kt_bf, vt_bf, nullptr);

  // img KI||VI batched (M=384 padded, N=3072)
  transpose_w3_kernel<<<dim3(48, 48, 2), tblk, 0, stream>>>(ca_kiw, ca_viw, nullptr, wsm, DIM, DIM);
  gemm_db_kernel<64><<<dim3(2 * DIM / 128, IMGP / 64), 256, 0, stream>>>(
      ctxi_bf, wsm, kivB, nullptr, nullptr, ctxkivF, nullptr, IMGP, 2 * DIM, DIM, 0, 1);
  rms_rope_multi_kernel<<<dim3(IMGP, 2), 256, 0, stream>>>(
      ctxkivF, 2 * DIM, 2, ca_nki, nullptr, 1, 0, 0, 1.0f, freqs, ki_bf, vi_bf, nullptr);

  // cross attn, ONE dispatch: bz 0,1 = txt K-chunks (slots 0,1 of txt softmax),
  // bz 2 = img softmax (slot 2). Combine merges 0,1 and ADDS 2.
  attn_kernel<<<dim3(SQ / 64, NHEADS, 3), 256, 0, stream>>>(
      q_bf, kt_bf, vt_bf, ki_bf, vi_bf, opart, mlbuf, T5, T5 / 2, 2, IMG, IMG);
  attn_combine_kernel<<<SQ, 256, 0, stream>>>(opart, mlbuf, act_bf, 2, 2);

  // x = x + attn2 @ ca_ow + ca_ob
  transpose_w3_kernel<<<dim3(48, 48, 1), tblk, 0, stream>>>(ca_ow, nullptr, nullptr, wsm, DIM, DIM);
  gemm_db_kernel<64><<<dim3(DIM / 128, SQ / 64), 256, 0, stream>>>(
      act_bf, wsm, ca_ob, nullptr, xcur, xcur, nullptr, SQ, DIM, DIM, 0, 1);

  // ---- FFN ----
  ln_mod_kernel<<<SQ, 256, 0, stream>>>(xcur, e4, e3, 1, act_bf);

  transpose_w3_kernel<<<dim3(FFN / 32, 48, 1), tblk, 0, stream>>>(ffn_w1, nullptr, nullptr, wbig, DIM, FFN);
  gemm_db_kernel<128><<<dim3(FFN / 128, SQ / 128), 256, 0, stream>>>(
      act_bf, wbig, ffn_b1, nullptr, nullptr, nullptr, y1, SQ, FFN, DIM, 1, 1);

  transpose_w3_kernel<<<dim3(48, FFN / 32, 1), tblk, 0, stream>>>(ffn_w2, nullptr, nullptr, wbig, FFN, DIM);
  gemm_db_kernel<128><<<dim3(DIM / 128, SQ / 128, 2), 256, 0, stream>>>(
      y1, wbig, nullptr, nullptr, nullptr, pbuf, nullptr, SQ, DIM, FFN, 0, 2);
  ffn2_reduce_kernel<<<(SQ * DIM + 255) / 256, 256, 0, stream>>>(
      pbuf, ffn_b2, e5, xcur, (float*)d_out);
}

// Round 8
// 1132.934 us; speedup vs baseline: 1.0982x; 1.0781x over previous
//
#include <hip/hip_runtime.h>
#include <stdint.h>

#define DIM 1536
#define NHEADS 12
#define HD 128
#define FFN 8960
#define SQ 3456
#define T5 512
#define LCTX 769
#define IMG 257
#define IMGP 384
#define EPSL 1e-6f

typedef __bf16 bf16;
typedef __bf16 bf16x8 __attribute__((ext_vector_type(8)));
typedef float f32x4 __attribute__((ext_vector_type(4)));

__device__ inline bf16x8 zero_bf16x8() {
  bf16x8 v;
  for (int i = 0; i < 8; i++) v[i] = (bf16)0.0f;
  return v;
}

// raw v_exp_f32 (2^x): exp2f is an OCML library call with guard code; the
// builtin lowers to the single transcendental instruction.
__device__ inline float fexp2(float x) {
#if __has_builtin(__builtin_amdgcn_exp2f)
  return __builtin_amdgcn_exp2f(x);
#else
  return exp2f(x);
#endif
}

// async 16B global -> LDS. lds base must be wave-uniform; lane i lands at lds + i*16.
__device__ inline void glds16(const bf16* g, bf16* lds) {
  __builtin_amdgcn_global_load_lds(
      (const __attribute__((address_space(1))) void*)g,
      (__attribute__((address_space(3))) void*)lds, 16, 0, 0);
}

// ---------------- small utility kernels ----------------

__global__ void prep_small_kernel(const float* __restrict__ modv, const float* __restrict__ e,
                                  float* __restrict__ e6f,
                                  const float* __restrict__ qb, const float* __restrict__ kb,
                                  const float* __restrict__ vb, float* __restrict__ qkvB,
                                  const float* __restrict__ ckb, const float* __restrict__ cvb,
                                  float* __restrict__ kvB,
                                  const float* __restrict__ kib, const float* __restrict__ vib,
                                  float* __restrict__ kivB) {
  int i = blockIdx.x * 256 + threadIdx.x;
  if (i < 6 * DIM) e6f[i] = modv[i] + e[i];
  if (i < DIM) {
    qkvB[i] = qb[i]; qkvB[i + DIM] = kb[i]; qkvB[i + 2 * DIM] = vb[i];
    kvB[i] = ckb[i]; kvB[i + DIM] = cvb[i];
    kivB[i] = kib[i]; kivB[i + DIM] = vib[i];
  }
}

// context -> bf16: txt rows 257..768 -> ctxt[512], img rows 0..256 -> ctxi[384] zero-padded
__global__ void prep_ctx_kernel(const float* __restrict__ ctx, bf16* __restrict__ ctxt,
                                bf16* __restrict__ ctxi) {
  int i = blockIdx.x * 256 + threadIdx.x;
  if (i < T5 * DIM) ctxt[i] = (bf16)ctx[(size_t)IMG * DIM + i];
  if (i < IMGP * DIM) {
    int r = i / DIM;
    ctxi[i] = (r < IMG) ? (bf16)ctx[i] : (bf16)0.0f;
  }
}

// transpose up to 3 weights W (K x N, f32) -> Wt (N x K, bf16), z selects source/dest slot.
__global__ void transpose_w3_kernel(const float* __restrict__ W0, const float* __restrict__ W1,
                                    const float* __restrict__ W2, bf16* __restrict__ Wt,
                                    int K, int N) {
  __shared__ float tile[32][33];
  const float* W = blockIdx.z == 0 ? W0 : (blockIdx.z == 1 ? W1 : W2);
  bf16* dst = Wt + (size_t)blockIdx.z * K * N;
  int n0 = blockIdx.x * 32, k0 = blockIdx.y * 32;
  int tx = threadIdx.x, ty = threadIdx.y;  // block (32,8)
  for (int i = ty; i < 32; i += 8)
    tile[i][tx] = W[(size_t)(k0 + i) * N + n0 + tx];
  __syncthreads();
  for (int i = ty; i < 32; i += 8)
    dst[(size_t)(n0 + i) * K + k0 + tx] = (bf16)tile[tx][i];
}

// block=256, two-value sum reduction broadcast to all threads
__device__ inline void block_reduce2(float& s1, float& s2) {
  __shared__ float buf[8];
  for (int off = 32; off; off >>= 1) {
    s1 += __shfl_down(s1, off, 64);
    s2 += __shfl_down(s2, off, 64);
  }
  int w = threadIdx.x >> 6;
  if ((threadIdx.x & 63) == 0) { buf[w] = s1; buf[w + 4] = s2; }
  __syncthreads();
  s1 = buf[0] + buf[1] + buf[2] + buf[3];
  s2 = buf[4] + buf[5] + buf[6] + buf[7];
  __syncthreads();
}

// y = LN(x) * (gamma (+1?)) + beta ; one block per row
__global__ __launch_bounds__(256) void ln_mod_kernel(
    const float* __restrict__ X, const float* __restrict__ gamma,
    const float* __restrict__ beta, int plus_one, bf16* __restrict__ out) {
  int r = blockIdx.x;
  const float* xr = X + (size_t)r * DIM;
  float v[6], s = 0.f, s2 = 0.f;
  for (int i = 0; i < 6; i++) {
    v[i] = xr[threadIdx.x + i * 256];
    s += v[i]; s2 += v[i] * v[i];
  }
  block_reduce2(s, s2);
  float mean = s * (1.0f / DIM);
  float var = s2 * (1.0f / DIM) - mean * mean;
  float rstd = rsqrtf(var + EPSL);
  float add1 = plus_one ? 1.0f : 0.0f;
  for (int i = 0; i < 6; i++) {
    int c = threadIdx.x + i * 256;
    out[(size_t)r * DIM + c] = (bf16)(((v[i] - mean) * rstd) * (gamma[c] + add1) + beta[c]);
  }
}

// fused per-row postprocess of a GEMM f32 output with row stride `istride`:
// blockIdx.y = section; per section: mode 0=cast, 1=rms, 2=rms+rope
// s0scale is folded into section-0 output (q pre-scaled by log2e/sqrt(HD) so
// the attention kernel's softmax runs in the exp2 domain with no per-score mul)
__global__ __launch_bounds__(256) void rms_rope_multi_kernel(
    const float* __restrict__ X, int istride, int nsec,
    const float* __restrict__ nw0, const float* __restrict__ nw1,
    int mode0, int mode1, int mode2, float s0scale,
    const float* __restrict__ freqs,
    bf16* __restrict__ o0, bf16* __restrict__ o1, bf16* __restrict__ o2) {
  int sec = blockIdx.y;
  int r = blockIdx.x;
  const float* xr = X + (size_t)r * istride + sec * DIM;
  const float* nw = sec == 0 ? nw0 : nw1;
  bf16* out = (sec == 0 ? o0 : (sec == 1 ? o1 : o2)) + (size_t)r * DIM;
  int mode = sec == 0 ? mode0 : (sec == 1 ? mode1 : mode2);
  float v[6];
  for (int i = 0; i < 6; i++) v[i] = xr[threadIdx.x + i * 256];
  if (mode == 0) {
    for (int i = 0; i < 6; i++) out[threadIdx.x + i * 256] = (bf16)v[i];
    return;
  }
  float s2 = 0.f, dummy = 0.f;
  for (int i = 0; i < 6; i++) s2 += v[i] * v[i];
  block_reduce2(s2, dummy);
  float rms = rsqrtf(s2 * (1.0f / DIM) + EPSL);
  if (sec == 0) rms *= s0scale;
  if (mode == 1) {
    for (int i = 0; i < 6; i++) {
      int c = threadIdx.x + i * 256;
      out[c] = (bf16)(v[i] * rms * nw[c]);
    }
  } else {
    int f = r / (18 * 24), rem = r % (18 * 24), hh = rem / 24, ww = rem % 24;
    for (int i = 0; i < 3; i++) {
      int p = threadIdx.x + i * 256;  // pair index
      int id = p & 63;
      int idx = id < 22 ? f : (id < 43 ? hh : ww);
      float th = freqs[idx * 64 + id];
      float cs = __cosf(th), sn = __sinf(th);
      float re = xr[2 * p] * rms * nw[2 * p];
      float im = xr[2 * p + 1] * rms * nw[2 * p + 1];
      out[2 * p]     = (bf16)(re * cs - im * sn);
      out[2 * p + 1] = (bf16)(re * sn + im * cs);
    }
  }
}

// FFN2 split-K reduce: out = xcur + (p0 + p1 + b2[col]) * e5[col]
__global__ void ffn2_reduce_kernel(const float* __restrict__ p, const float* __restrict__ b2,
                                   const float* __restrict__ e5, const float* __restrict__ xcur,
                                   float* __restrict__ out) {
  int i = blockIdx.x * 256 + threadIdx.x;
  if (i >= SQ * DIM) return;
  int col = i % DIM;
  out[i] = xcur[i] + (p[i] + p[i + (size_t)SQ * DIM] + b2[col]) * e5[col];
}

// ---------------- GEMM: C[M,N] = A[M,K](bf16) @ Wt[N,K]^T + epilogue ----------------
template <int BM>
__global__ __launch_bounds__(256) void gemm_db_kernel(
    const bf16* __restrict__ A, const bf16* __restrict__ Wt,
    const float* __restrict__ bias, const float* __restrict__ scalev,
    const float* __restrict__ resid, float* __restrict__ outF,
    bf16* __restrict__ outB, int M, int N, int K, int gelu, int ksplit) {
  constexpr int MI = BM / 32;
  constexpr int NAW = BM / 64;  // A glds per wave
  __shared__ bf16 As[2][BM * 32];
  __shared__ bf16 Bs[2][128 * 32];
  int tid = threadIdx.x;
  int tm0 = blockIdx.y * BM, tn0 = blockIdx.x * 128;
  int lane = tid & 63, wave = tid >> 6;
  int quad = lane >> 4, l16 = lane & 15;
  int mbase = (wave >> 1) * (BM / 2), nbase = (wave & 1) * 64;
  int lrow = lane >> 2, lcol = (lane & 3) * 8;
  int klen = K / ksplit;
  int kbeg = blockIdx.z * klen;

  const bf16* aP[NAW];
  const bf16* bP[2];
#pragma unroll
  for (int j = 0; j < NAW; j++) {
    int c = wave * NAW + j;
    aP[j] = A + (size_t)(tm0 + c * 16 + lrow) * K + kbeg + lcol;
  }
#pragma unroll
  for (int j = 0; j < 2; j++) {
    int c = wave * 2 + j;
    bP[j] = Wt + (size_t)(tn0 + c * 16 + lrow) * K + kbeg + lcol;
  }

  f32x4 acc[MI][4];
#pragma unroll
  for (int mi = 0; mi < MI; mi++)
    for (int ni = 0; ni < 4; ni++)
      for (int rr = 0; rr < 4; rr++) acc[mi][ni][rr] = 0.0f;

  auto stage = [&](int buf) {
#pragma unroll
    for (int j = 0; j < NAW; j++) {
      glds16(aP[j], &As[buf][(wave * NAW + j) * 512]);
      aP[j] += 32;
    }
#pragma unroll
    for (int j = 0; j < 2; j++) {
      glds16(bP[j], &Bs[buf][(wave * 2 + j) * 512]);
      bP[j] += 32;
    }
  };

  int niter = klen / 32;
  stage(0);
  int cur = 0;
  for (int it = 0; it < niter; it++) {
    __syncthreads();               // drains vmcnt: tile `cur` resident in LDS
    if (it + 1 < niter) stage(cur ^ 1);  // prefetch overlaps compute below
    bf16x8 af[MI], bfr[4];
#pragma unroll
    for (int mi = 0; mi < MI; mi++)
      af[mi] = *(bf16x8*)&As[cur][(mbase + mi * 16 + l16) * 32 + quad * 8];
#pragma unroll
    for (int ni = 0; ni < 4; ni++)
      bfr[ni] = *(bf16x8*)&Bs[cur][(nbase + ni * 16 + l16) * 32 + quad * 8];
#pragma unroll
    for (int mi = 0; mi < MI; mi++)
#pragma unroll
      for (int ni = 0; ni < 4; ni++)
        acc[mi][ni] = __builtin_amdgcn_mfma_f32_16x16x32_bf16(af[mi], bfr[ni], acc[mi][ni], 0, 0, 0);
    cur ^= 1;
  }

  if (ksplit > 1) {
    float* po = outF + (size_t)blockIdx.z * M * N;
#pragma unroll
    for (int mi = 0; mi < MI; mi++) {
      int rbase = tm0 + mbase + mi * 16 + quad * 4;
#pragma unroll
      for (int ni = 0; ni < 4; ni++) {
        int col = tn0 + nbase + ni * 16 + l16;
        for (int rr = 0; rr < 4; rr++)
          po[(size_t)(rbase + rr) * N + col] = acc[mi][ni][rr];
      }
    }
    return;
  }

#pragma unroll
  for (int mi = 0; mi < MI; mi++) {
    int rbase = tm0 + mbase + mi * 16 + quad * 4;
#pragma unroll
    for (int ni = 0; ni < 4; ni++) {
      int col = tn0 + nbase + ni * 16 + l16;
      float b = bias ? bias[col] : 0.0f;
      float sc = scalev ? scalev[col] : 1.0f;
      for (int rr = 0; rr < 4; rr++) {
        int row = rbase + rr;
        float t = acc[mi][ni][rr] + b;
        if (gelu) {
          float z = t;
          float u = 0.7978845608028654f * (z + 0.044715f * z * z * z);
          t = z / (1.0f + __expf(-2.0f * u));  // == 0.5z(1+tanh(u))
        }
        t *= sc;
        size_t idx = (size_t)row * N + col;
        if (resid) t += resid[idx];
        if (outF) outF[idx] = t;
        else outB[idx] = (bf16)t;
      }
    }
  }
}

// ---------------- Flash attention, K-split partials, 8 waves, QBLK=128 ----------------
// r7's verified pi-permuted layout (pi(nf*16+l16)=4*l16+nf on both P and V),
// restructured to 512-thread / 8-wave blocks over 128 q-rows:
//  - per-thread staging HALVES (2 K b128 + 8 packed V dwords) since the same
//    64-key tile now feeds 2x the q-rows; barrier drains per unit work halve.
//  - resident waves/CU ~6.5 -> 16 (LDS 54.3 KB -> 2-3 blocks x 8 waves),
//    addressing the measured 20% occupancy.
//  - exp2 via raw v_exp_f32 builtin (exp2f is a guarded OCML call).
// Bank math re-derived for the new mapping: K write (2srow+4scolc) uniform,
// V write (4j+2vl+vh) 2-lanes/bank, Ps b64/b128 uniform — all at minimum.
__global__ __launch_bounds__(512, 4) void attn_kernel(
    const bf16* __restrict__ Q, const bf16* __restrict__ Kb, const bf16* __restrict__ Vb,
    const bf16* __restrict__ Kb2, const bf16* __restrict__ Vb2,
    float* __restrict__ Opart, float* __restrict__ mlb,
    int L, int kchunk, int zsplit1, int Lsec, int kchunk2) {
  __shared__ __align__(16) bf16 Ks[64][136];
  __shared__ __align__(16) bf16 Vts[128][72];   // [d][pi(key)] rows 144 B
  __shared__ __align__(16) bf16 Ps[8][16][72];  // [wave][q-row][pi(key)] rows 144 B

  // m204 bijective XCD-contiguity swizzle (valid for ANY nwg, incl. 972)
  int nwg = gridDim.x * gridDim.y * gridDim.z;
  int flat = blockIdx.x + gridDim.x * (blockIdx.y + gridDim.y * blockIdx.z);
  {
    int xcd = flat & 7, g8 = flat >> 3, qq = nwg >> 3, r8 = nwg & 7;
    flat = (xcd < r8 ? xcd * (qq + 1) : r8 * (qq + 1) + (xcd - r8) * qq) + g8;
  }
  int bx = flat % gridDim.x;
  int rest = flat / gridDim.x;
  int hb = rest % gridDim.y;
  int bz = rest / gridDim.y;

  int tid = threadIdx.x;
  int q0 = bx * 128;
  int sec = bz >= zsplit1;
  int bzl = sec ? bz - zsplit1 : bz;
  const bf16* Kp = sec ? Kb2 : Kb;
  const bf16* Vp = sec ? Vb2 : Vb;
  int Lv = sec ? Lsec : L;
  int kch = sec ? kchunk2 : kchunk;
  int kbeg = bzl * kch;
  int kend = min(Lv, kbeg + kch);
  int klen = kend - kbeg;
  int zabs = bz;
  int lane = tid & 63, wave = tid >> 6;
  int quad = lane >> 4, l16 = lane & 15;
  int qrow = q0 + wave * 16 + l16;

  bf16x8 qf[4];
#pragma unroll
  for (int c = 0; c < 4; c++)
    qf[c] = *(const bf16x8*)(Q + (size_t)qrow * DIM + hb * HD + c * 32 + quad * 8);

  bf16x8 onesv;
#pragma unroll
  for (int i = 0; i < 8; i++) onesv[i] = (bf16)1.0f;

  f32x4 o[8];
#pragma unroll
  for (int ff = 0; ff < 8; ff++)
    for (int rr = 0; rr < 4; rr++) o[ff][rr] = 0.0f;
  float m_i[4], l_i[4];
#pragma unroll
  for (int r = 0; r < 4; r++) { m_i[r] = -1e30f; l_i[r] = 0.0f; }

  // K staging: 8 threads per key row; each loads 2x16B
  int srow = tid >> 3, scolc = tid & 7;
  // V staging: wave = d-group of 16 cols; within wave: (vl, vh) key pair, vd2 8-col half
  int low6 = tid & 63;
  int vh = low6 & 1, vd2 = (low6 >> 1) & 1, vl = low6 >> 2;
  int nt = (klen + 63) / 64;
  int tail = (klen & 63) != 0;

  const bf16* kp0 = Kp + (size_t)(kbeg + srow) * DIM + hb * HD + scolc * 8;
  const bf16* vp0 = Vp + (size_t)(kbeg + vh * 32 + vl) * DIM + hb * HD + wave * 16 + vd2 * 8;
  // V write base: byte (wave*16 + vd2*8 + j)*144 + pi-position (4*vl+2*vh)*2
  char* vwp = (char*)&Vts[0][0] + (wave * 16 + vd2 * 8) * 144 + (4 * vl + 2 * vh) * 2;

  bf16x8 kreg[2], va, vb;
  if (srow < klen) {
    kreg[0] = *(const bf16x8*)kp0;
    kreg[1] = *(const bf16x8*)(kp0 + 64);
  } else { kreg[0] = zero_bf16x8(); kreg[1] = zero_bf16x8(); }
  va = (vh * 32 + vl < klen) ? *(const bf16x8*)vp0 : zero_bf16x8();
  vb = (vh * 32 + vl + 16 < klen) ? *(const bf16x8*)(vp0 + 16 * DIM) : zero_bf16x8();

  for (int kt = 0; kt < nt; kt++) {
    __syncthreads();  // prev tile's LDS readers done
    *(bf16x8*)&Ks[srow][scolc * 8] = kreg[0];
    *(bf16x8*)&Ks[srow][scolc * 8 + 64] = kreg[1];
    {
      union U8 { bf16x8 v; uint32_t w[4]; };
      U8 ua, ub; ua.v = va; ub.v = vb;
#pragma unroll
      for (int j = 0; j < 8; j++) {
        uint32_t w0 = ua.w[j >> 1], w1 = ub.w[j >> 1];
        uint32_t pk = (j & 1) ? ((w0 >> 16) | (w1 & 0xFFFF0000u))
                              : ((w0 & 0xFFFFu) | (w1 << 16));
        *(uint32_t*)(vwp + j * 144) = pk;
      }
    }
    // prefetch next tile into registers; consumed after next loop-top barrier
    if (kt + 1 < nt) {
      int kb64 = (kt + 1) * 64;
      const bf16* kp = kp0 + (size_t)(kt + 1) * 64 * DIM;
      const bf16* vp = vp0 + (size_t)(kt + 1) * 64 * DIM;
      if (kb64 + srow < klen) {
        kreg[0] = *(const bf16x8*)kp;
        kreg[1] = *(const bf16x8*)(kp + 64);
      } else { kreg[0] = zero_bf16x8(); kreg[1] = zero_bf16x8(); }
      va = (kb64 + vh * 32 + vl < klen) ? *(const bf16x8*)vp : zero_bf16x8();
      vb = (kb64 + vh * 32 + vl + 16 < klen) ? *(const bf16x8*)(vp + 16 * DIM) : zero_bf16x8();
    }
    __syncthreads();  // staged tile visible

    f32x4 sfr[4];
    __builtin_amdgcn_s_setprio(1);
#pragma unroll
    for (int nf = 0; nf < 4; nf++) {
      f32x4 a;
      for (int rr = 0; rr < 4; rr++) a[rr] = 0.0f;
#pragma unroll
      for (int c = 0; c < 4; c++) {
        bf16x8 kf = *(bf16x8*)&Ks[nf * 16 + l16][c * 32 + quad * 8];
        a = __builtin_amdgcn_mfma_f32_16x16x32_bf16(qf[c], kf, a, 0, 0, 0);
      }
      sfr[nf] = a;
    }
    __builtin_amdgcn_s_setprio(0);

    if (tail && kt == nt - 1) {  // wave-uniform; only img (257) has a tail
#pragma unroll
      for (int nf = 0; nf < 4; nf++) {
        int colg = kt * 64 + nf * 16 + l16;
        bool valid = colg < klen;
#pragma unroll
        for (int r = 0; r < 4; r++)
          sfr[nf][r] = valid ? sfr[nf][r] : -1e30f;
      }
    }

    // defer-max: local per-lane max + one ballot; full chain only when needed
    float lmax[4];
#pragma unroll
    for (int r = 0; r < 4; r++)
      lmax[r] = fmaxf(fmaxf(sfr[0][r], sfr[1][r]), fmaxf(sfr[2][r], sfr[3][r]));
    int ok = (lmax[0] <= m_i[0] + 11.54f) & (lmax[1] <= m_i[1] + 11.54f) &
             (lmax[2] <= m_i[2] + 11.54f) & (lmax[3] <= m_i[3] + 11.54f);
    if (!__all(ok)) {
#pragma unroll
      for (int r = 0; r < 4; r++) {
        float t = lmax[r];
#pragma unroll
        for (int off = 1; off < 16; off <<= 1) t = fmaxf(t, __shfl_xor(t, off, 64));
        float mnew = fmaxf(m_i[r], t);
        float alpha = fexp2(m_i[r] - mnew);
        m_i[r] = mnew;
        l_i[r] *= alpha;
#pragma unroll
        for (int ff = 0; ff < 8; ff++) o[ff][r] *= alpha;
      }
    }

    // p = 2^(s - m); the lane's 4 values are pi-contiguous -> one b64 write/row
#pragma unroll
    for (int r = 0; r < 4; r++) {
      union { bf16 b[4]; unsigned long long u; } pk;
      pk.b[0] = (bf16)fexp2(sfr[0][r] - m_i[r]);
      pk.b[1] = (bf16)fexp2(sfr[1][r] - m_i[r]);
      pk.b[2] = (bf16)fexp2(sfr[2][r] - m_i[r]);
      pk.b[3] = (bf16)fexp2(sfr[3][r] - m_i[r]);
      *(unsigned long long*)((char*)&Ps[wave][quad * 4 + r][0] + l16 * 8) = pk.u;
    }
    // read P fragments (pi-ordered, contiguous b128)
    bf16x8 pf[2];
#pragma unroll
    for (int ks = 0; ks < 2; ks++)
      pf[ks] = *(bf16x8*)&Ps[wave][l16][ks * 32 + quad * 8];

    __builtin_amdgcn_s_setprio(1);
    // l-sum via MFMA with ones-B: D[row,*] = sum_k P[row,k]; lands in l_i layout
    f32x4 ld;
    for (int rr = 0; rr < 4; rr++) ld[rr] = 0.0f;
    ld = __builtin_amdgcn_mfma_f32_16x16x32_bf16(pf[0], onesv, ld, 0, 0, 0);
    ld = __builtin_amdgcn_mfma_f32_16x16x32_bf16(pf[1], onesv, ld, 0, 0, 0);
#pragma unroll
    for (int ff = 0; ff < 8; ff++) {
#pragma unroll
      for (int ks = 0; ks < 2; ks++) {
        bf16x8 vf = *(bf16x8*)&Vts[ff * 16 + l16][ks * 32 + quad * 8];
        o[ff] = __builtin_amdgcn_mfma_f32_16x16x32_bf16(pf[ks], vf, o[ff], 0, 0, 0);
      }
    }
    __builtin_amdgcn_s_setprio(0);
#pragma unroll
    for (int r = 0; r < 4; r++) l_i[r] += ld[r];
  }

  float* po = Opart + (size_t)zabs * SQ * DIM;
#pragma unroll
  for (int r = 0; r < 4; r++) {
    float inv = 1.0f / l_i[r];
#pragma unroll
    for (int ff = 0; ff < 8; ff++) o[ff][r] *= inv;
  }
#pragma unroll
  for (int ff = 0; ff < 8; ff++) {
#pragma unroll
    for (int r = 0; r < 4; r++) {
      int row = q0 + wave * 16 + quad * 4 + r;
      int col = hb * HD + ff * 16 + l16;
      po[(size_t)row * DIM + col] = o[ff][r];
    }
  }
  if (l16 == 0) {
#pragma unroll
    for (int r = 0; r < 4; r++) {
      int row = q0 + wave * 16 + quad * 4 + r;
      size_t mi = (((size_t)zabs * NHEADS + hb) * SQ + row) * 2;
      mlb[mi] = m_i[r];
      mlb[mi + 1] = l_i[r];
    }
  }
}

// Combine partial attention outputs (m values are in the exp2/log2 domain).
// Slots [0, nmerge) are flash-decoding partials of ONE softmax -> merged with
// weights w_z = l_z*2^(m_z-M)/sum. If addslot >= 0, that slot is a SEPARATE,
// already-normalized attention output that is ADDED (reference cross-attn is
// softmax(txt) + softmax(img), NOT a softmax over the union).
__global__ __launch_bounds__(256) void attn_combine_kernel(
    const float* __restrict__ Op, const float* __restrict__ mlb,
    bf16* __restrict__ out, int nmerge, int addslot) {
  int row = blockIdx.x;
  __shared__ float wsh[3 * NHEADS];
  int t = threadIdx.x;
  if (t < NHEADS) {
    float m[3], l[3];
    for (int z = 0; z < 3; z++) {
      if (z < nmerge) {
        size_t b = (((size_t)z * NHEADS + t) * SQ + row) * 2;
        m[z] = mlb[b]; l[z] = mlb[b + 1];
      } else {
        m[z] = -1e30f; l[z] = 0.0f;
      }
    }
    float M = fmaxf(m[0], fmaxf(m[1], m[2]));
    float w0 = l[0] * fexp2(m[0] - M);
    float w1 = l[1] * fexp2(m[1] - M);
    float w2 = l[2] * fexp2(m[2] - M);
    float inv = 1.0f / (w0 + w1 + w2);
    wsh[t] = w0 * inv;
    wsh[NHEADS + t] = w1 * inv;
    wsh[2 * NHEADS + t] = w2 * inv;
  }
  __syncthreads();
#pragma unroll
  for (int i = 0; i < 6; i++) {
    int c = t + i * 256;
    int h = c >> 7;
    float acc = wsh[h] * Op[((size_t)0 * SQ + row) * DIM + c];
    if (nmerge > 1) acc += wsh[NHEADS + h] * Op[((size_t)1 * SQ + row) * DIM + c];
    if (nmerge > 2) acc += wsh[2 * NHEADS + h] * Op[((size_t)2 * SQ + row) * DIM + c];
    if (addslot >= 0) acc += Op[((size_t)addslot * SQ + row) * DIM + c];
    out[(size_t)row * DIM + c] = (bf16)acc;
  }
}

// ---------------- host orchestration ----------------

extern "C" void kernel_launch(void* const* d_in, const int* in_sizes, int n_in,
                              void* d_out, int out_size, void* d_ws, size_t ws_size,
                              hipStream_t stream) {
  const float* x      = (const float*)d_in[0];
  const float* e      = (const float*)d_in[1];
  const float* ctx    = (const float*)d_in[2];
  const float* freqs  = (const float*)d_in[3];
  const float* modv   = (const float*)d_in[4];
  const float* sa_qw  = (const float*)d_in[5];
  const float* sa_qb  = (const float*)d_in[6];
  const float* sa_kw  = (const float*)d_in[7];
  const float* sa_kb  = (const float*)d_in[8];
  const float* sa_vw  = (const float*)d_in[9];
  const float* sa_vb  = (const float*)d_in[10];
  const float* sa_ow  = (const float*)d_in[11];
  const float* sa_ob  = (const float*)d_in[12];
  const float* sa_nq  = (const float*)d_in[13];
  const float* sa_nk  = (const float*)d_in[14];
  const float* norm3w = (const float*)d_in[15];
  const float* norm3b = (const float*)d_in[16];
  const float* ca_qw  = (const float*)d_in[17];
  const float* ca_qb  = (const float*)d_in[18];
  const float* ca_kw  = (const float*)d_in[19];
  const float* ca_kb  = (const float*)d_in[20];
  const float* ca_vw  = (const float*)d_in[21];
  const float* ca_vb  = (const float*)d_in[22];
  const float* ca_kiw = (const float*)d_in[23];
  const float* ca_kib = (const float*)d_in[24];
  const float* ca_viw = (const float*)d_in[25];
  const float* ca_vib = (const float*)d_in[26];
  const float* ca_ow  = (const float*)d_in[27];
  const float* ca_ob  = (const float*)d_in[28];
  const float* ca_nq  = (const float*)d_in[29];
  const float* ca_nk  = (const float*)d_in[30];
  const float* ca_nki = (const float*)d_in[31];
  const float* ffn_w1 = (const float*)d_in[32];
  const float* ffn_b1 = (const float*)d_in[33];
  const float* ffn_w2 = (const float*)d_in[34];
  const float* ffn_b2 = (const float*)d_in[35];

  char* ws = (char*)d_ws;
  size_t off = 0;
  auto alloc = [&](size_t bytes) -> void* {
    void* p = ws + off;
    off += (bytes + 255) & ~(size_t)255;
    return p;
  };
  float* e6f   = (float*)alloc((size_t)6 * DIM * 4);
  bf16* act_bf = (bf16*)alloc((size_t)SQ * DIM * 2);
  bf16* q_bf   = (bf16*)alloc((size_t)SQ * DIM * 2);
  bf16* k_bf   = (bf16*)alloc((size_t)SQ * DIM * 2);
  bf16* v_bf   = (bf16*)alloc((size_t)SQ * DIM * 2);
  // big0 shared region: qkvF [SQ,4608] f32 -> attn partials [3][SQ,DIM] f32
  //   -> projf [SQ,DIM] f32 -> cross partials -> y1 [SQ,FFN] bf16
  char* big0   = (char*)alloc((size_t)SQ * 3 * DIM * 4);
  float* xcur  = (float*)alloc((size_t)SQ * DIM * 4);
  bf16* wbig   = (bf16*)alloc((size_t)FFN * DIM * 2);     // qkvT / w1T / w2T (sequential reuse)
  bf16* wsm    = (bf16*)alloc((size_t)3 * DIM * DIM * 2); // owT/qT/kvT (sequential reuse)
  bf16* ctxt_bf = (bf16*)alloc((size_t)T5 * DIM * 2);
  bf16* ctxi_bf = (bf16*)alloc((size_t)IMGP * DIM * 2);
  float* ctxkvF = (float*)alloc((size_t)T5 * 2 * DIM * 4);
  float* ctxkivF = (float*)alloc((size_t)IMGP * 2 * DIM * 4);
  bf16* kt_bf  = (bf16*)alloc((size_t)T5 * DIM * 2);
  bf16* vt_bf  = (bf16*)alloc((size_t)T5 * DIM * 2);
  bf16* ki_bf  = (bf16*)alloc((size_t)IMGP * DIM * 2);
  bf16* vi_bf  = (bf16*)alloc((size_t)IMGP * DIM * 2);
  float* qkvB  = (float*)alloc((size_t)3 * DIM * 4);
  float* kvB   = (float*)alloc((size_t)2 * DIM * 4);
  float* kivB  = (float*)alloc((size_t)2 * DIM * 4);
  float* mlbuf = (float*)alloc((size_t)3 * NHEADS * SQ * 2 * 4);

  float* qkvF = (float*)big0;
  float* projf = (float*)big0;
  float* opart = (float*)big0;
  bf16* y1 = (bf16*)big0;
  float* pbuf = (float*)act_bf;  // FFN2 split-K partials (act/q/k/v dead by then)

  const float* e0 = e6f;
  const float* e1 = e6f + DIM;
  const float* e2 = e6f + 2 * DIM;
  const float* e3 = e6f + 3 * DIM;
  const float* e4 = e6f + 4 * DIM;
  const float* e5 = e6f + 5 * DIM;

  // log2(e)/sqrt(HD): q pre-scale putting softmax in the exp2 domain
  const float SCL2 = 0.12751744f;

  dim3 tblk(32, 8);

  prep_small_kernel<<<(6 * DIM + 255) / 256, 256, 0, stream>>>(
      modv, e, e6f, sa_qb, sa_kb, sa_vb, qkvB, ca_kb, ca_vb, kvB, ca_kib, ca_vib, kivB);

  // xs = LN(x)*(1+e1)+e0
  ln_mod_kernel<<<SQ, 256, 0, stream>>>(x, e1, e0, 1, act_bf);

  // ---- self attention: batched QKV ----
  transpose_w3_kernel<<<dim3(48, 48, 3), tblk, 0, stream>>>(sa_qw, sa_kw, sa_vw, wbig, DIM, DIM);
  gemm_db_kernel<128><<<dim3(3 * DIM / 128, SQ / 128), 256, 0, stream>>>(
      act_bf, wbig, qkvB, nullptr, nullptr, qkvF, nullptr, SQ, 3 * DIM, DIM, 0, 1);
  rms_rope_multi_kernel<<<dim3(SQ, 3), 256, 0, stream>>>(
      qkvF, 3 * DIM, 3, sa_nq, sa_nk, 2, 2, 0, SCL2, freqs, q_bf, k_bf, v_bf);

  // K-split flash attention: 3 chunks of 1152 keys -> partials in big0 (qkvF dead)
  attn_kernel<<<dim3(SQ / 128, NHEADS, 3), 512, 0, stream>>>(
      q_bf, k_bf, v_bf, k_bf, v_bf, opart, mlbuf, SQ, SQ / 3, 3, SQ, SQ / 3);
  attn_combine_kernel<<<SQ, 256, 0, stream>>>(opart, mlbuf, act_bf, 3, -1);

  // x = x + (attn @ sa_ow + sa_ob) * e2
  transpose_w3_kernel<<<dim3(48, 48, 1), tblk, 0, stream>>>(sa_ow, nullptr, nullptr, wsm, DIM, DIM);
  gemm_db_kernel<64><<<dim3(DIM / 128, SQ / 64), 256, 0, stream>>>(
      act_bf, wsm, sa_ob, e2, x, xcur, nullptr, SQ, DIM, DIM, 0, 1);

  // ---- cross attention ----
  ln_mod_kernel<<<SQ, 256, 0, stream>>>(xcur, norm3w, norm3b, 0, act_bf);

  transpose_w3_kernel<<<dim3(48, 48, 1), tblk, 0, stream>>>(ca_qw, nullptr, nullptr, wsm, DIM, DIM);
  gemm_db_kernel<64><<<dim3(DIM / 128, SQ / 64), 256, 0, stream>>>(
      act_bf, wsm, ca_qb, nullptr, nullptr, projf, nullptr, SQ, DIM, DIM, 0, 1);
  rms_rope_multi_kernel<<<dim3(SQ, 1), 256, 0, stream>>>(
      projf, DIM, 1, ca_nq, nullptr, 1, 0, 0, SCL2, freqs, q_bf, nullptr, nullptr);

  prep_ctx_kernel<<<(T5 * DIM + 255) / 256, 256, 0, stream>>>(ctx, ctxt_bf, ctxi_bf);

  // txt K||V batched (M=512, N=3072)
  transpose_w3_kernel<<<dim3(48, 48, 2), tblk, 0, stream>>>(ca_kw, ca_vw, nullptr, wsm, DIM, DIM);
  gemm_db_kernel<64><<<dim3(2 * DIM / 128, T5 / 64), 256, 0, stream>>>(
      ctxt_bf, wsm, kvB, nullptr, nullptr, ctxkvF, nullptr, T5, 2 * DIM, DIM, 0, 1);
  rms_rope_multi_kernel<<<dim3(T5, 2), 256, 0, stream>>>(
      ctxkvF, 2 * DIM, 2, ca_nk, nullptr, 1, 0, 0, 1.0f, freqs, kt_bf, vt_bf, nullptr);

  // img KI||VI batched (M=384 padded, N=3072)
  transpose_w3_kernel<<<dim3(48, 48, 2), tblk, 0, stream>>>(ca_kiw, ca_viw, nullptr, wsm, DIM, DIM);
  gemm_db_kernel<64><<<dim3(2 * DIM / 128, IMGP / 64), 256, 0, stream>>>(
      ctxi_bf, wsm, kivB, nullptr, nullptr, ctxkivF, nullptr, IMGP, 2 * DIM, DIM, 0, 1);
  rms_rope_multi_kernel<<<dim3(IMGP, 2), 256, 0, stream>>>(
      ctxkivF, 2 * DIM, 2, ca_nki, nullptr, 1, 0, 0, 1.0f, freqs, ki_bf, vi_bf, nullptr);

  // cross attn, ONE dispatch: bz 0,1 = txt K-chunks (slots 0,1 of txt softmax),
  // bz 2 = img softmax (slot 2). Combine merges 0,1 and ADDS 2.
  attn_kernel<<<dim3(SQ / 128, NHEADS, 3), 512, 0, stream>>>(
      q_bf, kt_bf, vt_bf, ki_bf, vi_bf, opart, mlbuf, T5, T5 / 2, 2, IMG, IMG);
  attn_combine_kernel<<<SQ, 256, 0, stream>>>(opart, mlbuf, act_bf, 2, 2);

  // x = x + attn2 @ ca_ow + ca_ob
  transpose_w3_kernel<<<dim3(48, 48, 1), tblk, 0, stream>>>(ca_ow, nullptr, nullptr, wsm, DIM, DIM);
  gemm_db_kernel<64><<<dim3(DIM / 128, SQ / 64), 256, 0, stream>>>(
      act_bf, wsm, ca_ob, nullptr, xcur, xcur, nullptr, SQ, DIM, DIM, 0, 1);

  // ---- FFN ----
  ln_mod_kernel<<<SQ, 256, 0, stream>>>(xcur, e4, e3, 1, act_bf);

  transpose_w3_kernel<<<dim3(FFN / 32, 48, 1), tblk, 0, stream>>>(ffn_w1, nullptr, nullptr, wbig, DIM, FFN);
  gemm_db_kernel<128><<<dim3(FFN / 128, SQ / 128), 256, 0, stream>>>(
      act_bf, wbig, ffn_b1, nullptr, nullptr, nullptr, y1, SQ, FFN, DIM, 1, 1);

  transpose_w3_kernel<<<dim3(48, FFN / 32, 1), tblk, 0, stream>>>(ffn_w2, nullptr, nullptr, wbig, FFN, DIM);
  gemm_db_kernel<128><<<dim3(DIM / 128, SQ / 128, 2), 256, 0, stream>>>(
      y1, wbig, nullptr, nullptr, nullptr, pbuf, nullptr, SQ, DIM, FFN, 0, 2);
  ffn2_reduce_kernel<<<(SQ * DIM + 255) / 256, 256, 0, stream>>>(
      pbuf, ffn_b2, e5, xcur, (float*)d_out);
}

// Round 9
// 1105.778 us; speedup vs baseline: 1.1251x; 1.0246x over previous
//
#include <hip/hip_runtime.h>
#include <stdint.h>

#define DIM 1536
#define NHEADS 12
#define HD 128
#define FFN 8960
#define SQ 3456
#define T5 512
#define LCTX 769
#define IMG 257
#define IMGP 384
#define EPSL 1e-6f

typedef __bf16 bf16;
typedef __bf16 bf16x8 __attribute__((ext_vector_type(8)));
typedef float f32x4 __attribute__((ext_vector_type(4)));

__device__ inline bf16x8 zero_bf16x8() {
  bf16x8 v;
  for (int i = 0; i < 8; i++) v[i] = (bf16)0.0f;
  return v;
}

// raw v_exp_f32 (2^x): exp2f is an OCML library call with guard code; the
// builtin lowers to the single transcendental instruction.
__device__ inline float fexp2(float x) {
#if __has_builtin(__builtin_amdgcn_exp2f)
  return __builtin_amdgcn_exp2f(x);
#else
  return exp2f(x);
#endif
}

// async 16B global -> LDS. lds base must be wave-uniform; lane i lands at lds + i*16.
__device__ inline void glds16(const bf16* g, bf16* lds) {
  __builtin_amdgcn_global_load_lds(
      (const __attribute__((address_space(1))) void*)g,
      (__attribute__((address_space(3))) void*)lds, 16, 0, 0);
}

// ---------------- small utility kernels ----------------

__global__ void prep_small_kernel(const float* __restrict__ modv, const float* __restrict__ e,
                                  float* __restrict__ e6f,
                                  const float* __restrict__ qb, const float* __restrict__ kb,
                                  const float* __restrict__ vb, float* __restrict__ qkvB,
                                  const float* __restrict__ ckb, const float* __restrict__ cvb,
                                  float* __restrict__ kvB,
                                  const float* __restrict__ kib, const float* __restrict__ vib,
                                  float* __restrict__ kivB) {
  int i = blockIdx.x * 256 + threadIdx.x;
  if (i < 6 * DIM) e6f[i] = modv[i] + e[i];
  if (i < DIM) {
    qkvB[i] = qb[i]; qkvB[i + DIM] = kb[i]; qkvB[i + 2 * DIM] = vb[i];
    kvB[i] = ckb[i]; kvB[i + DIM] = cvb[i];
    kivB[i] = kib[i]; kivB[i + DIM] = vib[i];
  }
}

// context -> bf16: txt rows 257..768 -> ctxt[512], img rows 0..256 -> ctxi[384] zero-padded
__global__ void prep_ctx_kernel(const float* __restrict__ ctx, bf16* __restrict__ ctxt,
                                bf16* __restrict__ ctxi) {
  int i = blockIdx.x * 256 + threadIdx.x;
  if (i < T5 * DIM) ctxt[i] = (bf16)ctx[(size_t)IMG * DIM + i];
  if (i < IMGP * DIM) {
    int r = i / DIM;
    ctxi[i] = (r < IMG) ? (bf16)ctx[i] : (bf16)0.0f;
  }
}

// transpose up to 3 weights W (K x N, f32) -> Wt (N x K, bf16), z selects source/dest slot.
__global__ void transpose_w3_kernel(const float* __restrict__ W0, const float* __restrict__ W1,
                                    const float* __restrict__ W2, bf16* __restrict__ Wt,
                                    int K, int N) {
  __shared__ float tile[32][33];
  const float* W = blockIdx.z == 0 ? W0 : (blockIdx.z == 1 ? W1 : W2);
  bf16* dst = Wt + (size_t)blockIdx.z * K * N;
  int n0 = blockIdx.x * 32, k0 = blockIdx.y * 32;
  int tx = threadIdx.x, ty = threadIdx.y;  // block (32,8)
  for (int i = ty; i < 32; i += 8)
    tile[i][tx] = W[(size_t)(k0 + i) * N + n0 + tx];
  __syncthreads();
  for (int i = ty; i < 32; i += 8)
    dst[(size_t)(n0 + i) * K + k0 + tx] = (bf16)tile[tx][i];
}

// block=256, two-value sum reduction broadcast to all threads
__device__ inline void block_reduce2(float& s1, float& s2) {
  __shared__ float buf[8];
  for (int off = 32; off; off >>= 1) {
    s1 += __shfl_down(s1, off, 64);
    s2 += __shfl_down(s2, off, 64);
  }
  int w = threadIdx.x >> 6;
  if ((threadIdx.x & 63) == 0) { buf[w] = s1; buf[w + 4] = s2; }
  __syncthreads();
  s1 = buf[0] + buf[1] + buf[2] + buf[3];
  s2 = buf[4] + buf[5] + buf[6] + buf[7];
  __syncthreads();
}

// y = LN(x) * (gamma (+1?)) + beta ; one block per row
__global__ __launch_bounds__(256) void ln_mod_kernel(
    const float* __restrict__ X, const float* __restrict__ gamma,
    const float* __restrict__ beta, int plus_one, bf16* __restrict__ out) {
  int r = blockIdx.x;
  const float* xr = X + (size_t)r * DIM;
  float v[6], s = 0.f, s2 = 0.f;
  for (int i = 0; i < 6; i++) {
    v[i] = xr[threadIdx.x + i * 256];
    s += v[i]; s2 += v[i] * v[i];
  }
  block_reduce2(s, s2);
  float mean = s * (1.0f / DIM);
  float var = s2 * (1.0f / DIM) - mean * mean;
  float rstd = rsqrtf(var + EPSL);
  float add1 = plus_one ? 1.0f : 0.0f;
  for (int i = 0; i < 6; i++) {
    int c = threadIdx.x + i * 256;
    out[(size_t)r * DIM + c] = (bf16)(((v[i] - mean) * rstd) * (gamma[c] + add1) + beta[c]);
  }
}

// fused per-row postprocess of a GEMM f32 output with row stride `istride`:
// blockIdx.y = section; per section: mode 0=cast, 1=rms, 2=rms+rope
// s0scale is folded into section-0 output (q pre-scaled by log2e/sqrt(HD) so
// the attention kernel's softmax runs in the exp2 domain with no per-score mul)
__global__ __launch_bounds__(256) void rms_rope_multi_kernel(
    const float* __restrict__ X, int istride, int nsec,
    const float* __restrict__ nw0, const float* __restrict__ nw1,
    int mode0, int mode1, int mode2, float s0scale,
    const float* __restrict__ freqs,
    bf16* __restrict__ o0, bf16* __restrict__ o1, bf16* __restrict__ o2) {
  int sec = blockIdx.y;
  int r = blockIdx.x;
  const float* xr = X + (size_t)r * istride + sec * DIM;
  const float* nw = sec == 0 ? nw0 : nw1;
  bf16* out = (sec == 0 ? o0 : (sec == 1 ? o1 : o2)) + (size_t)r * DIM;
  int mode = sec == 0 ? mode0 : (sec == 1 ? mode1 : mode2);
  float v[6];
  for (int i = 0; i < 6; i++) v[i] = xr[threadIdx.x + i * 256];
  if (mode == 0) {
    for (int i = 0; i < 6; i++) out[threadIdx.x + i * 256] = (bf16)v[i];
    return;
  }
  float s2 = 0.f, dummy = 0.f;
  for (int i = 0; i < 6; i++) s2 += v[i] * v[i];
  block_reduce2(s2, dummy);
  float rms = rsqrtf(s2 * (1.0f / DIM) + EPSL);
  if (sec == 0) rms *= s0scale;
  if (mode == 1) {
    for (int i = 0; i < 6; i++) {
      int c = threadIdx.x + i * 256;
      out[c] = (bf16)(v[i] * rms * nw[c]);
    }
  } else {
    int f = r / (18 * 24), rem = r % (18 * 24), hh = rem / 24, ww = rem % 24;
    for (int i = 0; i < 3; i++) {
      int p = threadIdx.x + i * 256;  // pair index
      int id = p & 63;
      int idx = id < 22 ? f : (id < 43 ? hh : ww);
      float th = freqs[idx * 64 + id];
      float cs = __cosf(th), sn = __sinf(th);
      float re = xr[2 * p] * rms * nw[2 * p];
      float im = xr[2 * p + 1] * rms * nw[2 * p + 1];
      out[2 * p]     = (bf16)(re * cs - im * sn);
      out[2 * p + 1] = (bf16)(re * sn + im * cs);
    }
  }
}

// FFN2 split-K reduce: out = xcur + (p0 + p1 + b2[col]) * e5[col]
__global__ void ffn2_reduce_kernel(const float* __restrict__ p, const float* __restrict__ b2,
                                   const float* __restrict__ e5, const float* __restrict__ xcur,
                                   float* __restrict__ out) {
  int i = blockIdx.x * 256 + threadIdx.x;
  if (i >= SQ * DIM) return;
  int col = i % DIM;
  out[i] = xcur[i] + (p[i] + p[i + (size_t)SQ * DIM] + b2[col]) * e5[col];
}

// ---------------- GEMM: C[M,N] = A[M,K](bf16) @ Wt[N,K]^T + epilogue ----------------
// Reuse-oriented XCD swizzle (round-9): remap the flat block id with the m204
// chunk-per-XCD bijection over a STRIPE-MAJOR logical order (stripes of Wx
// N-tiles, all M-tiles inside). Each XCD then works a stable ~Wx-B-panel set
// (~Wx*0.4 MB, L2-resident) while A-panels stream once per window — cuts the
// measured 214 MB/dispatch L2-miss traffic (38 MB unique) roughly in half.
template <int BM>
__global__ __launch_bounds__(256) void gemm_db_kernel(
    const bf16* __restrict__ A, const bf16* __restrict__ Wt,
    const float* __restrict__ bias, const float* __restrict__ scalev,
    const float* __restrict__ resid, float* __restrict__ outF,
    bf16* __restrict__ outB, int M, int N, int K, int gelu, int ksplit) {
  constexpr int MI = BM / 32;
  constexpr int NAW = BM / 64;  // A glds per wave
  __shared__ bf16 As[2][BM * 32];
  __shared__ bf16 Bs[2][128 * 32];
  int tid = threadIdx.x;

  // ---- block swizzle ----
  int gx = gridDim.x, gy = gridDim.y;
  int nwg = gx * gy * gridDim.z;
  int f = blockIdx.x + gx * (blockIdx.y + gy * blockIdx.z);
  {
    int xcd = f & 7, g8 = f >> 3, qq = nwg >> 3, r8 = nwg & 7;
    f = (xcd < r8 ? xcd * (qq + 1) : r8 * (qq + 1) + (xcd - r8) * qq) + g8;
  }
  int bz = f / (gx * gy);
  int i2 = f % (gx * gy);
  int wx = 1;
  for (int w = (gx < 10 ? gx : 10); w > 1; --w)
    if (gx % w == 0) { wx = w; break; }
  int sw = gy * wx;                 // blocks per stripe
  int stripe = i2 / sw, rem2 = i2 % sw;
  int by = rem2 / wx;
  int bx = stripe * wx + rem2 % wx;

  int tm0 = by * BM, tn0 = bx * 128;
  int lane = tid & 63, wave = tid >> 6;
  int quad = lane >> 4, l16 = lane & 15;
  int mbase = (wave >> 1) * (BM / 2), nbase = (wave & 1) * 64;
  int lrow = lane >> 2, lcol = (lane & 3) * 8;
  int klen = K / ksplit;
  int kbeg = bz * klen;

  const bf16* aP[NAW];
  const bf16* bP[2];
#pragma unroll
  for (int j = 0; j < NAW; j++) {
    int c = wave * NAW + j;
    aP[j] = A + (size_t)(tm0 + c * 16 + lrow) * K + kbeg + lcol;
  }
#pragma unroll
  for (int j = 0; j < 2; j++) {
    int c = wave * 2 + j;
    bP[j] = Wt + (size_t)(tn0 + c * 16 + lrow) * K + kbeg + lcol;
  }

  f32x4 acc[MI][4];
#pragma unroll
  for (int mi = 0; mi < MI; mi++)
    for (int ni = 0; ni < 4; ni++)
      for (int rr = 0; rr < 4; rr++) acc[mi][ni][rr] = 0.0f;

  auto stage = [&](int buf) {
#pragma unroll
    for (int j = 0; j < NAW; j++) {
      glds16(aP[j], &As[buf][(wave * NAW + j) * 512]);
      aP[j] += 32;
    }
#pragma unroll
    for (int j = 0; j < 2; j++) {
      glds16(bP[j], &Bs[buf][(wave * 2 + j) * 512]);
      bP[j] += 32;
    }
  };

  int niter = klen / 32;
  stage(0);
  int cur = 0;
  for (int it = 0; it < niter; it++) {
    __syncthreads();               // drains vmcnt: tile `cur` resident in LDS
    if (it + 1 < niter) stage(cur ^ 1);  // prefetch overlaps compute below
    bf16x8 af[MI], bfr[4];
#pragma unroll
    for (int mi = 0; mi < MI; mi++)
      af[mi] = *(bf16x8*)&As[cur][(mbase + mi * 16 + l16) * 32 + quad * 8];
#pragma unroll
    for (int ni = 0; ni < 4; ni++)
      bfr[ni] = *(bf16x8*)&Bs[cur][(nbase + ni * 16 + l16) * 32 + quad * 8];
#pragma unroll
    for (int mi = 0; mi < MI; mi++)
#pragma unroll
      for (int ni = 0; ni < 4; ni++)
        acc[mi][ni] = __builtin_amdgcn_mfma_f32_16x16x32_bf16(af[mi], bfr[ni], acc[mi][ni], 0, 0, 0);
    cur ^= 1;
  }

  if (ksplit > 1) {
    float* po = outF + (size_t)bz * M * N;
#pragma unroll
    for (int mi = 0; mi < MI; mi++) {
      int rbase = tm0 + mbase + mi * 16 + quad * 4;
#pragma unroll
      for (int ni = 0; ni < 4; ni++) {
        int col = tn0 + nbase + ni * 16 + l16;
        for (int rr = 0; rr < 4; rr++)
          po[(size_t)(rbase + rr) * N + col] = acc[mi][ni][rr];
      }
    }
    return;
  }

#pragma unroll
  for (int mi = 0; mi < MI; mi++) {
    int rbase = tm0 + mbase + mi * 16 + quad * 4;
#pragma unroll
    for (int ni = 0; ni < 4; ni++) {
      int col = tn0 + nbase + ni * 16 + l16;
      float b = bias ? bias[col] : 0.0f;
      float sc = scalev ? scalev[col] : 1.0f;
      for (int rr = 0; rr < 4; rr++) {
        int row = rbase + rr;
        float t = acc[mi][ni][rr] + b;
        if (gelu) {
          float z = t;
          float u = 0.7978845608028654f * (z + 0.044715f * z * z * z);
          t = z / (1.0f + __expf(-2.0f * u));  // == 0.5z(1+tanh(u))
        }
        t *= sc;
        size_t idx = (size_t)row * N + col;
        if (resid) t += resid[idx];
        if (outF) outF[idx] = t;
        else outB[idx] = (bf16)t;
      }
    }
  }
}

// ---------------- Flash attention, K-split partials, 8 waves, QBLK=128 ----------------
// (unchanged from round 8 — verified at 1133 µs total)
__global__ __launch_bounds__(512, 4) void attn_kernel(
    const bf16* __restrict__ Q, const bf16* __restrict__ Kb, const bf16* __restrict__ Vb,
    const bf16* __restrict__ Kb2, const bf16* __restrict__ Vb2,
    float* __restrict__ Opart, float* __restrict__ mlb,
    int L, int kchunk, int zsplit1, int Lsec, int kchunk2) {
  __shared__ __align__(16) bf16 Ks[64][136];
  __shared__ __align__(16) bf16 Vts[128][72];   // [d][pi(key)] rows 144 B
  __shared__ __align__(16) bf16 Ps[8][16][72];  // [wave][q-row][pi(key)] rows 144 B

  // m204 bijective XCD-contiguity swizzle (valid for ANY nwg)
  int nwg = gridDim.x * gridDim.y * gridDim.z;
  int flat = blockIdx.x + gridDim.x * (blockIdx.y + gridDim.y * blockIdx.z);
  {
    int xcd = flat & 7, g8 = flat >> 3, qq = nwg >> 3, r8 = nwg & 7;
    flat = (xcd < r8 ? xcd * (qq + 1) : r8 * (qq + 1) + (xcd - r8) * qq) + g8;
  }
  int bx = flat % gridDim.x;
  int rest = flat / gridDim.x;
  int hb = rest % gridDim.y;
  int bz = rest / gridDim.y;

  int tid = threadIdx.x;
  int q0 = bx * 128;
  int sec = bz >= zsplit1;
  int bzl = sec ? bz - zsplit1 : bz;
  const bf16* Kp = sec ? Kb2 : Kb;
  const bf16* Vp = sec ? Vb2 : Vb;
  int Lv = sec ? Lsec : L;
  int kch = sec ? kchunk2 : kchunk;
  int kbeg = bzl * kch;
  int kend = min(Lv, kbeg + kch);
  int klen = kend - kbeg;
  int zabs = bz;
  int lane = tid & 63, wave = tid >> 6;
  int quad = lane >> 4, l16 = lane & 15;
  int qrow = q0 + wave * 16 + l16;

  bf16x8 qf[4];
#pragma unroll
  for (int c = 0; c < 4; c++)
    qf[c] = *(const bf16x8*)(Q + (size_t)qrow * DIM + hb * HD + c * 32 + quad * 8);

  bf16x8 onesv;
#pragma unroll
  for (int i = 0; i < 8; i++) onesv[i] = (bf16)1.0f;

  f32x4 o[8];
#pragma unroll
  for (int ff = 0; ff < 8; ff++)
    for (int rr = 0; rr < 4; rr++) o[ff][rr] = 0.0f;
  float m_i[4], l_i[4];
#pragma unroll
  for (int r = 0; r < 4; r++) { m_i[r] = -1e30f; l_i[r] = 0.0f; }

  // K staging: 8 threads per key row; each loads 2x16B
  int srow = tid >> 3, scolc = tid & 7;
  // V staging: wave = d-group of 16 cols; within wave: (vl, vh) key pair, vd2 8-col half
  int low6 = tid & 63;
  int vh = low6 & 1, vd2 = (low6 >> 1) & 1, vl = low6 >> 2;
  int nt = (klen + 63) / 64;
  int tail = (klen & 63) != 0;

  const bf16* kp0 = Kp + (size_t)(kbeg + srow) * DIM + hb * HD + scolc * 8;
  const bf16* vp0 = Vp + (size_t)(kbeg + vh * 32 + vl) * DIM + hb * HD + wave * 16 + vd2 * 8;
  // V write base: byte (wave*16 + vd2*8 + j)*144 + pi-position (4*vl+2*vh)*2
  char* vwp = (char*)&Vts[0][0] + (wave * 16 + vd2 * 8) * 144 + (4 * vl + 2 * vh) * 2;

  bf16x8 kreg[2], va, vb;
  if (srow < klen) {
    kreg[0] = *(const bf16x8*)kp0;
    kreg[1] = *(const bf16x8*)(kp0 + 64);
  } else { kreg[0] = zero_bf16x8(); kreg[1] = zero_bf16x8(); }
  va = (vh * 32 + vl < klen) ? *(const bf16x8*)vp0 : zero_bf16x8();
  vb = (vh * 32 + vl + 16 < klen) ? *(const bf16x8*)(vp0 + 16 * DIM) : zero_bf16x8();

  for (int kt = 0; kt < nt; kt++) {
    __syncthreads();  // prev tile's LDS readers done
    *(bf16x8*)&Ks[srow][scolc * 8] = kreg[0];
    *(bf16x8*)&Ks[srow][scolc * 8 + 64] = kreg[1];
    {
      union U8 { bf16x8 v; uint32_t w[4]; };
      U8 ua, ub; ua.v = va; ub.v = vb;
#pragma unroll
      for (int j = 0; j < 8; j++) {
        uint32_t w0 = ua.w[j >> 1], w1 = ub.w[j >> 1];
        uint32_t pk = (j & 1) ? ((w0 >> 16) | (w1 & 0xFFFF0000u))
                              : ((w0 & 0xFFFFu) | (w1 << 16));
        *(uint32_t*)(vwp + j * 144) = pk;
      }
    }
    // prefetch next tile into registers; consumed after next loop-top barrier
    if (kt + 1 < nt) {
      int kb64 = (kt + 1) * 64;
      const bf16* kp = kp0 + (size_t)(kt + 1) * 64 * DIM;
      const bf16* vp = vp0 + (size_t)(kt + 1) * 64 * DIM;
      if (kb64 + srow < klen) {
        kreg[0] = *(const bf16x8*)kp;
        kreg[1] = *(const bf16x8*)(kp + 64);
      } else { kreg[0] = zero_bf16x8(); kreg[1] = zero_bf16x8(); }
      va = (kb64 + vh * 32 + vl < klen) ? *(const bf16x8*)vp : zero_bf16x8();
      vb = (kb64 + vh * 32 + vl + 16 < klen) ? *(const bf16x8*)(vp + 16 * DIM) : zero_bf16x8();
    }
    __syncthreads();  // staged tile visible

    f32x4 sfr[4];
    __builtin_amdgcn_s_setprio(1);
#pragma unroll
    for (int nf = 0; nf < 4; nf++) {
      f32x4 a;
      for (int rr = 0; rr < 4; rr++) a[rr] = 0.0f;
#pragma unroll
      for (int c = 0; c < 4; c++) {
        bf16x8 kf = *(bf16x8*)&Ks[nf * 16 + l16][c * 32 + quad * 8];
        a = __builtin_amdgcn_mfma_f32_16x16x32_bf16(qf[c], kf, a, 0, 0, 0);
      }
      sfr[nf] = a;
    }
    __builtin_amdgcn_s_setprio(0);

    if (tail && kt == nt - 1) {  // wave-uniform; only img (257) has a tail
#pragma unroll
      for (int nf = 0; nf < 4; nf++) {
        int colg = kt * 64 + nf * 16 + l16;
        bool valid = colg < klen;
#pragma unroll
        for (int r = 0; r < 4; r++)
          sfr[nf][r] = valid ? sfr[nf][r] : -1e30f;
      }
    }

    // defer-max: local per-lane max + one ballot; full chain only when needed
    float lmax[4];
#pragma unroll
    for (int r = 0; r < 4; r++)
      lmax[r] = fmaxf(fmaxf(sfr[0][r], sfr[1][r]), fmaxf(sfr[2][r], sfr[3][r]));
    int ok = (lmax[0] <= m_i[0] + 11.54f) & (lmax[1] <= m_i[1] + 11.54f) &
             (lmax[2] <= m_i[2] + 11.54f) & (lmax[3] <= m_i[3] + 11.54f);
    if (!__all(ok)) {
#pragma unroll
      for (int r = 0; r < 4; r++) {
        float t = lmax[r];
#pragma unroll
        for (int off = 1; off < 16; off <<= 1) t = fmaxf(t, __shfl_xor(t, off, 64));
        float mnew = fmaxf(m_i[r], t);
        float alpha = fexp2(m_i[r] - mnew);
        m_i[r] = mnew;
        l_i[r] *= alpha;
#pragma unroll
        for (int ff = 0; ff < 8; ff++) o[ff][r] *= alpha;
      }
    }

    // p = 2^(s - m); the lane's 4 values are pi-contiguous -> one b64 write/row
#pragma unroll
    for (int r = 0; r < 4; r++) {
      union { bf16 b[4]; unsigned long long u; } pk;
      pk.b[0] = (bf16)fexp2(sfr[0][r] - m_i[r]);
      pk.b[1] = (bf16)fexp2(sfr[1][r] - m_i[r]);
      pk.b[2] = (bf16)fexp2(sfr[2][r] - m_i[r]);
      pk.b[3] = (bf16)fexp2(sfr[3][r] - m_i[r]);
      *(unsigned long long*)((char*)&Ps[wave][quad * 4 + r][0] + l16 * 8) = pk.u;
    }
    // read P fragments (pi-ordered, contiguous b128)
    bf16x8 pf[2];
#pragma unroll
    for (int ks = 0; ks < 2; ks++)
      pf[ks] = *(bf16x8*)&Ps[wave][l16][ks * 32 + quad * 8];

    __builtin_amdgcn_s_setprio(1);
    // l-sum via MFMA with ones-B: D[row,*] = sum_k P[row,k]; lands in l_i layout
    f32x4 ld;
    for (int rr = 0; rr < 4; rr++) ld[rr] = 0.0f;
    ld = __builtin_amdgcn_mfma_f32_16x16x32_bf16(pf[0], onesv, ld, 0, 0, 0);
    ld = __builtin_amdgcn_mfma_f32_16x16x32_bf16(pf[1], onesv, ld, 0, 0, 0);
#pragma unroll
    for (int ff = 0; ff < 8; ff++) {
#pragma unroll
      for (int ks = 0; ks < 2; ks++) {
        bf16x8 vf = *(bf16x8*)&Vts[ff * 16 + l16][ks * 32 + quad * 8];
        o[ff] = __builtin_amdgcn_mfma_f32_16x16x32_bf16(pf[ks], vf, o[ff], 0, 0, 0);
      }
    }
    __builtin_amdgcn_s_setprio(0);
#pragma unroll
    for (int r = 0; r < 4; r++) l_i[r] += ld[r];
  }

  float* po = Opart + (size_t)zabs * SQ * DIM;
#pragma unroll
  for (int r = 0; r < 4; r++) {
    float inv = 1.0f / l_i[r];
#pragma unroll
    for (int ff = 0; ff < 8; ff++) o[ff][r] *= inv;
  }
#pragma unroll
  for (int ff = 0; ff < 8; ff++) {
#pragma unroll
    for (int r = 0; r < 4; r++) {
      int row = q0 + wave * 16 + quad * 4 + r;
      int col = hb * HD + ff * 16 + l16;
      po[(size_t)row * DIM + col] = o[ff][r];
    }
  }
  if (l16 == 0) {
#pragma unroll
    for (int r = 0; r < 4; r++) {
      int row = q0 + wave * 16 + quad * 4 + r;
      size_t mi = (((size_t)zabs * NHEADS + hb) * SQ + row) * 2;
      mlb[mi] = m_i[r];
      mlb[mi + 1] = l_i[r];
    }
  }
}

// Combine partial attention outputs (m values are in the exp2/log2 domain).
// Slots [0, nmerge) are flash-decoding partials of ONE softmax -> merged with
// weights w_z = l_z*2^(m_z-M)/sum. If addslot >= 0, that slot is a SEPARATE,
// already-normalized attention output that is ADDED (reference cross-attn is
// softmax(txt) + softmax(img), NOT a softmax over the union).
__global__ __launch_bounds__(256) void attn_combine_kernel(
    const float* __restrict__ Op, const float* __restrict__ mlb,
    bf16* __restrict__ out, int nmerge, int addslot) {
  int row = blockIdx.x;
  __shared__ float wsh[3 * NHEADS];
  int t = threadIdx.x;
  if (t < NHEADS) {
    float m[3], l[3];
    for (int z = 0; z < 3; z++) {
      if (z < nmerge) {
        size_t b = (((size_t)z * NHEADS + t) * SQ + row) * 2;
        m[z] = mlb[b]; l[z] = mlb[b + 1];
      } else {
        m[z] = -1e30f; l[z] = 0.0f;
      }
    }
    float M = fmaxf(m[0], fmaxf(m[1], m[2]));
    float w0 = l[0] * fexp2(m[0] - M);
    float w1 = l[1] * fexp2(m[1] - M);
    float w2 = l[2] * fexp2(m[2] - M);
    float inv = 1.0f / (w0 + w1 + w2);
    wsh[t] = w0 * inv;
    wsh[NHEADS + t] = w1 * inv;
    wsh[2 * NHEADS + t] = w2 * inv;
  }
  __syncthreads();
#pragma unroll
  for (int i = 0; i < 6; i++) {
    int c = t + i * 256;
    int h = c >> 7;
    float acc = wsh[h] * Op[((size_t)0 * SQ + row) * DIM + c];
    if (nmerge > 1) acc += wsh[NHEADS + h] * Op[((size_t)1 * SQ + row) * DIM + c];
    if (nmerge > 2) acc += wsh[2 * NHEADS + h] * Op[((size_t)2 * SQ + row) * DIM + c];
    if (addslot >= 0) acc += Op[((size_t)addslot * SQ + row) * DIM + c];
    out[(size_t)row * DIM + c] = (bf16)acc;
  }
}

// ---------------- host orchestration ----------------

extern "C" void kernel_launch(void* const* d_in, const int* in_sizes, int n_in,
                              void* d_out, int out_size, void* d_ws, size_t ws_size,
                              hipStream_t stream) {
  const float* x      = (const float*)d_in[0];
  const float* e      = (const float*)d_in[1];
  const float* ctx    = (const float*)d_in[2];
  const float* freqs  = (const float*)d_in[3];
  const float* modv   = (const float*)d_in[4];
  const float* sa_qw  = (const float*)d_in[5];
  const float* sa_qb  = (const float*)d_in[6];
  const float* sa_kw  = (const float*)d_in[7];
  const float* sa_kb  = (const float*)d_in[8];
  const float* sa_vw  = (const float*)d_in[9];
  const float* sa_vb  = (const float*)d_in[10];
  const float* sa_ow  = (const float*)d_in[11];
  const float* sa_ob  = (const float*)d_in[12];
  const float* sa_nq  = (const float*)d_in[13];
  const float* sa_nk  = (const float*)d_in[14];
  const float* norm3w = (const float*)d_in[15];
  const float* norm3b = (const float*)d_in[16];
  const float* ca_qw  = (const float*)d_in[17];
  const float* ca_qb  = (const float*)d_in[18];
  const float* ca_kw  = (const float*)d_in[19];
  const float* ca_kb  = (const float*)d_in[20];
  const float* ca_vw  = (const float*)d_in[21];
  const float* ca_vb  = (const float*)d_in[22];
  const float* ca_kiw = (const float*)d_in[23];
  const float* ca_kib = (const float*)d_in[24];
  const float* ca_viw = (const float*)d_in[25];
  const float* ca_vib = (const float*)d_in[26];
  const float* ca_ow  = (const float*)d_in[27];
  const float* ca_ob  = (const float*)d_in[28];
  const float* ca_nq  = (const float*)d_in[29];
  const float* ca_nk  = (const float*)d_in[30];
  const float* ca_nki = (const float*)d_in[31];
  const float* ffn_w1 = (const float*)d_in[32];
  const float* ffn_b1 = (const float*)d_in[33];
  const float* ffn_w2 = (const float*)d_in[34];
  const float* ffn_b2 = (const float*)d_in[35];

  char* ws = (char*)d_ws;
  size_t off = 0;
  auto alloc = [&](size_t bytes) -> void* {
    void* p = ws + off;
    off += (bytes + 255) & ~(size_t)255;
    return p;
  };
  float* e6f   = (float*)alloc((size_t)6 * DIM * 4);
  bf16* act_bf = (bf16*)alloc((size_t)SQ * DIM * 2);
  bf16* q_bf   = (bf16*)alloc((size_t)SQ * DIM * 2);
  bf16* k_bf   = (bf16*)alloc((size_t)SQ * DIM * 2);
  bf16* v_bf   = (bf16*)alloc((size_t)SQ * DIM * 2);
  // big0 shared region: qkvF [SQ,4608] f32 -> attn partials [3][SQ,DIM] f32
  //   -> projf [SQ,DIM] f32 -> cross partials -> y1 [SQ,FFN] bf16
  char* big0   = (char*)alloc((size_t)SQ * 3 * DIM * 4);
  float* xcur  = (float*)alloc((size_t)SQ * DIM * 4);
  bf16* wbig   = (bf16*)alloc((size_t)FFN * DIM * 2);     // qkvT / w1T / w2T (sequential reuse)
  bf16* wsm    = (bf16*)alloc((size_t)3 * DIM * DIM * 2); // owT/qT/kvT (sequential reuse)
  bf16* ctxt_bf = (bf16*)alloc((size_t)T5 * DIM * 2);
  bf16* ctxi_bf = (bf16*)alloc((size_t)IMGP * DIM * 2);
  float* ctxkvF = (float*)alloc((size_t)T5 * 2 * DIM * 4);
  float* ctxkivF = (float*)alloc((size_t)IMGP * 2 * DIM * 4);
  bf16* kt_bf  = (bf16*)alloc((size_t)T5 * DIM * 2);
  bf16* vt_bf  = (bf16*)alloc((size_t)T5 * DIM * 2);
  bf16* ki_bf  = (bf16*)alloc((size_t)IMGP * DIM * 2);
  bf16* vi_bf  = (bf16*)alloc((size_t)IMGP * DIM * 2);
  float* qkvB  = (float*)alloc((size_t)3 * DIM * 4);
  float* kvB   = (float*)alloc((size_t)2 * DIM * 4);
  float* kivB  = (float*)alloc((size_t)2 * DIM * 4);
  float* mlbuf = (float*)alloc((size_t)3 * NHEADS * SQ * 2 * 4);

  float* qkvF = (float*)big0;
  float* projf = (float*)big0;
  float* opart = (float*)big0;
  bf16* y1 = (bf16*)big0;
  float* pbuf = (float*)act_bf;  // FFN2 split-K partials (act/q/k/v dead by then)

  const float* e0 = e6f;
  const float* e1 = e6f + DIM;
  const float* e2 = e6f + 2 * DIM;
  const float* e3 = e6f + 3 * DIM;
  const float* e4 = e6f + 4 * DIM;
  const float* e5 = e6f + 5 * DIM;

  // log2(e)/sqrt(HD): q pre-scale putting softmax in the exp2 domain
  const float SCL2 = 0.12751744f;

  dim3 tblk(32, 8);

  prep_small_kernel<<<(6 * DIM + 255) / 256, 256, 0, stream>>>(
      modv, e, e6f, sa_qb, sa_kb, sa_vb, qkvB, ca_kb, ca_vb, kvB, ca_kib, ca_vib, kivB);

  // xs = LN(x)*(1+e1)+e0
  ln_mod_kernel<<<SQ, 256, 0, stream>>>(x, e1, e0, 1, act_bf);

  // ---- self attention: batched QKV ----
  transpose_w3_kernel<<<dim3(48, 48, 3), tblk, 0, stream>>>(sa_qw, sa_kw, sa_vw, wbig, DIM, DIM);
  gemm_db_kernel<128><<<dim3(3 * DIM / 128, SQ / 128), 256, 0, stream>>>(
      act_bf, wbig, qkvB, nullptr, nullptr, qkvF, nullptr, SQ, 3 * DIM, DIM, 0, 1);
  rms_rope_multi_kernel<<<dim3(SQ, 3), 256, 0, stream>>>(
      qkvF, 3 * DIM, 3, sa_nq, sa_nk, 2, 2, 0, SCL2, freqs, q_bf, k_bf, v_bf);

  // K-split flash attention: 3 chunks of 1152 keys -> partials in big0 (qkvF dead)
  attn_kernel<<<dim3(SQ / 128, NHEADS, 3), 512, 0, stream>>>(
      q_bf, k_bf, v_bf, k_bf, v_bf, opart, mlbuf, SQ, SQ / 3, 3, SQ, SQ / 3);
  attn_combine_kernel<<<SQ, 256, 0, stream>>>(opart, mlbuf, act_bf, 3, -1);

  // x = x + (attn @ sa_ow + sa_ob) * e2
  transpose_w3_kernel<<<dim3(48, 48, 1), tblk, 0, stream>>>(sa_ow, nullptr, nullptr, wsm, DIM, DIM);
  gemm_db_kernel<64><<<dim3(DIM / 128, SQ / 64), 256, 0, stream>>>(
      act_bf, wsm, sa_ob, e2, x, xcur, nullptr, SQ, DIM, DIM, 0, 1);

  // ---- cross attention ----
  ln_mod_kernel<<<SQ, 256, 0, stream>>>(xcur, norm3w, norm3b, 0, act_bf);

  transpose_w3_kernel<<<dim3(48, 48, 1), tblk, 0, stream>>>(ca_qw, nullptr, nullptr, wsm, DIM, DIM);
  gemm_db_kernel<64><<<dim3(DIM / 128, SQ / 64), 256, 0, stream>>>(
      act_bf, wsm, ca_qb, nullptr, nullptr, projf, nullptr, SQ, DIM, DIM, 0, 1);
  rms_rope_multi_kernel<<<dim3(SQ, 1), 256, 0, stream>>>(
      projf, DIM, 1, ca_nq, nullptr, 1, 0, 0, SCL2, freqs, q_bf, nullptr, nullptr);

  prep_ctx_kernel<<<(T5 * DIM + 255) / 256, 256, 0, stream>>>(ctx, ctxt_bf, ctxi_bf);

  // txt K||V batched (M=512, N=3072)
  transpose_w3_kernel<<<dim3(48, 48, 2), tblk, 0, stream>>>(ca_kw, ca_vw, nullptr, wsm, DIM, DIM);
  gemm_db_kernel<64><<<dim3(2 * DIM / 128, T5 / 64), 256, 0, stream>>>(
      ctxt_bf, wsm, kvB, nullptr, nullptr, ctxkvF, nullptr, T5, 2 * DIM, DIM, 0, 1);
  rms_rope_multi_kernel<<<dim3(T5, 2), 256, 0, stream>>>(
      ctxkvF, 2 * DIM, 2, ca_nk, nullptr, 1, 0, 0, 1.0f, freqs, kt_bf, vt_bf, nullptr);

  // img KI||VI batched (M=384 padded, N=3072)
  transpose_w3_kernel<<<dim3(48, 48, 2), tblk, 0, stream>>>(ca_kiw, ca_viw, nullptr, wsm, DIM, DIM);
  gemm_db_kernel<64><<<dim3(2 * DIM / 128, IMGP / 64), 256, 0, stream>>>(
      ctxi_bf, wsm, kivB, nullptr, nullptr, ctxkivF, nullptr, IMGP, 2 * DIM, DIM, 0, 1);
  rms_rope_multi_kernel<<<dim3(IMGP, 2), 256, 0, stream>>>(
      ctxkivF, 2 * DIM, 2, ca_nki, nullptr, 1, 0, 0, 1.0f, freqs, ki_bf, vi_bf, nullptr);

  // cross attn, ONE dispatch: bz 0,1 = txt K-chunks (slots 0,1 of txt softmax),
  // bz 2 = img softmax (slot 2). Combine merges 0,1 and ADDS 2.
  attn_kernel<<<dim3(SQ / 128, NHEADS, 3), 512, 0, stream>>>(
      q_bf, kt_bf, vt_bf, ki_bf, vi_bf, opart, mlbuf, T5, T5 / 2, 2, IMG, IMG);
  attn_combine_kernel<<<SQ, 256, 0, stream>>>(opart, mlbuf, act_bf, 2, 2);

  // x = x + attn2 @ ca_ow + ca_ob
  transpose_w3_kernel<<<dim3(48, 48, 1), tblk, 0, stream>>>(ca_ow, nullptr, nullptr, wsm, DIM, DIM);
  gemm_db_kernel<64><<<dim3(DIM / 128, SQ / 64), 256, 0, stream>>>(
      act_bf, wsm, ca_ob, nullptr, xcur, xcur, nullptr, SQ, DIM, DIM, 0, 1);

  // ---- FFN ----
  ln_mod_kernel<<<SQ, 256, 0, stream>>>(xcur, e4, e3, 1, act_bf);

  transpose_w3_kernel<<<dim3(FFN / 32, 48, 1), tblk, 0, stream>>>(ffn_w1, nullptr, nullptr, wbig, DIM, FFN);
  gemm_db_kernel<128><<<dim3(FFN / 128, SQ / 128), 256, 0, stream>>>(
      act_bf, wbig, ffn_b1, nullptr, nullptr, nullptr, y1, SQ, FFN, DIM, 1, 1);

  transpose_w3_kernel<<<dim3(48, FFN / 32, 1), tblk, 0, stream>>>(ffn_w2, nullptr, nullptr, wbig, FFN, DIM);
  gemm_db_kernel<128><<<dim3(DIM / 128, SQ / 128, 2), 256, 0, stream>>>(
      y1, wbig, nullptr, nullptr, nullptr, pbuf, nullptr, SQ, DIM, FFN, 0, 2);
  ffn2_reduce_kernel<<<(SQ * DIM + 255) / 256, 256, 0, stream>>>(
      pbuf, ffn_b2, e5, xcur, (float*)d_out);
}